// Round 4
// baseline (2869.800 us; speedup 1.0000x reference)
//
#include <hip/hip_runtime.h>

#define N_NODES  100000
#define N_EDGES  1600000
#define N_GRAPHS 1024
#define D        128
#define BN_EPS   1e-5f

// --- geometry: 512 blocks x 512 thr = 2 blocks/CU, co-residency GUARANTEED
// (2 x 52224B LDS = 104KB <= 160KB; 16 waves <= 32; VGPR capped 128 via
// __launch_bounds__(512,4); total capacity >= 3/CU so greedy placement of 512
// blocks can never strand one). Normal launch + hand-rolled device-scope
// barrier replaces hipLaunchCooperativeKernel, which R14/R15 forensics showed
// was refused outright (absmax == max|ref| == 272 => output all zeros).
#define GRID      512
#define THREADS   512
#define GTOT      (GRID * THREADS)          // 262144

// --- atomic-free CSR build geometry ---
#define FNSLICE      98                     // ceil(100000/1024) node slices
#define FSLICE_NODES 1024
#define FSLICE_CAP   20480                  // mean 16327, sigma~127
#define QCAP         64                     // per-block bin: mean 31.9 (+5.7σ)
#define CCHUNK       3125                   // 512*3125 == 1600000 exactly

// --- setup work ranges (grid-stride gtid) ---
#define CVT_ITEMS    1600000                // 100000*128/8
#define PW_ITEMS     98304                  // 6*128*128
#define FOLD_BASE    PW_ITEMS
#define GST_BASE     (PW_ITEMS + 768)
#define MISC_BASE    (GST_BASE + 1025)

#define N_TILES      1563                   // ceil(100000/64)

typedef short bf16x8 __attribute__((ext_vector_type(8)));
typedef float f32x4  __attribute__((ext_vector_type(4)));

__device__ __forceinline__ ushort f2bf(float f) {        // RNE fp32->bf16
    unsigned int b = __float_as_uint(f);
    return (ushort)((b + 0x7fffu + ((b >> 16) & 1u)) >> 16);
}
__device__ __forceinline__ float bflo(unsigned int u) { return __uint_as_float(u << 16); }
__device__ __forceinline__ float bfhi(unsigned int u) { return __uint_as_float(u & 0xffff0000u); }
__device__ __forceinline__ unsigned int packbf(float x, float y) {
    return (unsigned int)f2bf(x) | ((unsigned int)f2bf(y) << 16);
}

struct MegaArgs {
    const float* x;
    const int*   src;
    const int*   dst;
    const int*   batch;
    const float* W1;  const float* b1;
    const float* gamma; const float* beta; const float* mean; const float* var;
    const float* W2;  const float* b2;
    const float* hW1; const float* hb1; const float* hW2; const float* hb2;
    float*       out;
    ushort*      buf0; ushort* buf1;
    ushort*      Wt;   float*  folds;
    unsigned int* squeue;
    int* csr_src; int* offsets; int* slice_tail; int* gstart;
    unsigned int* bar;          // [0]=arrival count, [1]=generation (memset 0)
};

// Sense-reversing grid barrier, device-scope. All blocks co-resident by
// construction (grid 512 <= guaranteed 2/CU * 256). Release: every thread
// fences (agent) so its writes are L2-written-back, then thread 0 joins an
// ACQ_REL RMW chain on bar[0]; last arrival resets the count and
// release-stores a new generation; spinners acquire-load it. Acquire: every
// thread fences so subsequent reads skip stale L1/L2 lines (XCDs not coherent).
__device__ __forceinline__ void gridbar(unsigned int* bar) {
    __threadfence();                        // release my writes to agent scope
    __syncthreads();                        // whole block fenced + arrived
    if (threadIdx.x == 0) {
        unsigned int g = __hip_atomic_load(&bar[1], __ATOMIC_RELAXED,
                                           __HIP_MEMORY_SCOPE_AGENT);
        unsigned int a = __hip_atomic_fetch_add(&bar[0], 1u, __ATOMIC_ACQ_REL,
                                                __HIP_MEMORY_SCOPE_AGENT);
        if (a == GRID - 1) {
            __hip_atomic_store(&bar[0], 0u, __ATOMIC_RELAXED,
                               __HIP_MEMORY_SCOPE_AGENT);
            __hip_atomic_store(&bar[1], g + 1u, __ATOMIC_RELEASE,
                               __HIP_MEMORY_SCOPE_AGENT);
        } else {
            while (__hip_atomic_load(&bar[1], __ATOMIC_ACQUIRE,
                                     __HIP_MEMORY_SCOPE_AGENT) == g)
                __builtin_amdgcn_s_sleep(2);
        }
    }
    __syncthreads();
    __threadfence();                        // acquire: invalidate stale caches
}

// One kernel, phases separated by gridbar():
//   setup -> compact -> fill -> [gather -> gemm]x3 -> pool
// R13 lesson: gather bandwidth scales with continuously-issuing waves; the
// gather phase here is pure (no LDS, no block barriers) at 16 waves/CU.
__global__ __launch_bounds__(THREADS, 4) void gin_mega(MegaArgs A) {
    __shared__ __align__(16) char smem[52224];   // phase-aliased union

    const int t    = threadIdx.x;
    const int bid  = blockIdx.x;
    const int gtid = bid * THREADS + t;
    const int lane = t & 63, wv = t >> 6;        // 8 waves/block

    // ================= phase 0: setup (cvt + W^T + folds + gstart + misc) ====
    for (int i = gtid; i < CVT_ITEMS; i += GTOT) {           // x -> bf16
        size_t p = (size_t)i * 8;
        float4 v0 = *(const float4*)(A.x + p);
        float4 v1 = *(const float4*)(A.x + p + 4);
        uint4 o;
        o.x = packbf(v0.x, v0.y); o.y = packbf(v0.z, v0.w);
        o.z = packbf(v1.x, v1.y); o.w = packbf(v1.z, v1.w);
        *(uint4*)(A.buf0 + p) = o;
    }
    if (gtid < PW_ITEMS) {                                   // W -> bf16 transposed
        int i = gtid >> 14, r = gtid & 16383;
        int n = r >> 7, k = r & 127, l = i >> 1;
        const float* W = (i & 1) ? (A.W2 + (size_t)l * D * D) : (A.W1 + (size_t)l * D * D);
        A.Wt[gtid] = f2bf(W[k * D + n]);
    }
    {
        int fi = gtid - FOLD_BASE;                           // BN folds
        if (fi >= 0 && fi < 6 * D) {
            int i = fi >> 7, j = fi & 127, l = i >> 1;
            float s, o;
            if ((i & 1) == 0) {
                float sv = A.gamma[l * D + j] * rsqrtf(A.var[l * D + j] + BN_EPS);
                s = sv;
                o = (A.b1[l * D + j] - A.mean[l * D + j]) * sv + A.beta[l * D + j];
            } else {
                s = 1.0f;
                o = A.b2[l * D + j];
            }
            A.folds[(size_t)i * 2 * D + j]     = s;
            A.folds[(size_t)i * 2 * D + D + j] = o;
        }
        int gi = gtid - GST_BASE;                            // gstart binary search
        if (gi >= 0 && gi <= N_GRAPHS) {
            int lo = 0, hi = N_NODES;
            while (lo < hi) {
                int mid = (lo + hi) >> 1;
                if (A.batch[mid] < gi) lo = mid + 1; else hi = mid;
            }
            A.gstart[gi] = lo;
        }
        int mi = gtid - MISC_BASE;                           // misc inits
        if (mi >= 0 && mi < FNSLICE) A.slice_tail[mi] = 0;
        if (mi == FNSLICE) A.offsets[N_NODES] = N_EDGES;
    }
    gridbar(A.bar);

    // ================= phase 1: compact (bin edges by 1024-node slice) =======
    {
        unsigned int* qbuf = (unsigned int*)smem;            // 98*64*4 = 25088
        int* qcnt  = (int*)(smem + 25088);                   // 98
        int* qbase = (int*)(smem + 25480);                   // 98
        if (t < FNSLICE) qcnt[t] = 0;
        __syncthreads();
        int e0 = bid * CCHUNK;
        int eend = e0 + CCHUNK; if (eend > N_EDGES) eend = N_EDGES;
        for (int e = e0 + t; e < eend; e += THREADS) {
            int d = A.dst[e], s = A.src[e];
            int sl = d >> 10;
            unsigned int pk = ((unsigned int)(d & 1023) << 17) | (unsigned int)s;
            int pos = atomicAdd(&qcnt[sl], 1);
            if (pos < QCAP) qbuf[sl * QCAP + pos] = pk;
            else {  // rare by construction: direct spill, still correct
                int gp = atomicAdd(&A.slice_tail[sl], 1);
                A.squeue[(size_t)sl * FSLICE_CAP + gp] = pk;
            }
        }
        __syncthreads();
        if (t < FNSLICE) {
            int n = qcnt[t]; if (n > QCAP) n = QCAP;
            qbase[t] = atomicAdd(&A.slice_tail[t], n);
        }
        __syncthreads();
        for (int sl = wv; sl < FNSLICE; sl += 8) {
            int n = qcnt[sl]; if (n > QCAP) n = QCAP;
            int gb = qbase[sl];
            for (int i = lane; i < n; i += 64)
                A.squeue[(size_t)sl * FSLICE_CAP + gb + i] = qbuf[sl * QCAP + i];
        }
    }
    gridbar(A.bar);

    // ================= phase 2: fill (per-slice hist -> scan -> scatter) =====
    if (bid < FNSLICE) {
        int* hist  = (int*)smem;                             // 1024
        int* cur   = (int*)(smem + 4096);                    // 1024
        int* sbase = (int*)(smem + 8192);                    // 128
        int* wsum  = (int*)(smem + 8704);                    // 8
        int sl = bid;
        int n = A.slice_tail[sl];
        if (t < 128) sbase[t] = (t < FNSLICE) ? A.slice_tail[t] : 0;
        hist[t] = 0; hist[t + 512] = 0;
        __syncthreads();
        for (int off = 1; off < 128; off <<= 1) {            // scan slice totals
            int u = (t < 128 && t >= off) ? sbase[t - off] : 0;
            __syncthreads();
            if (t < 128) sbase[t] += u;
            __syncthreads();
        }
        int gbase = (sl == 0) ? 0 : sbase[sl - 1];
        size_t qb = (size_t)sl * FSLICE_CAP;
        for (int i = t; i < n; i += THREADS)
            atomicAdd(&hist[A.squeue[qb + i] >> 17], 1);
        __syncthreads();
        int c0 = hist[2 * t], c1 = hist[2 * t + 1], c = c0 + c1;
        int sc = c;
#pragma unroll
        for (int off = 1; off < 64; off <<= 1) {             // wave-inclusive scan
            int u = __shfl_up(sc, off, 64);
            if (lane >= off) sc += u;
        }
        if (lane == 63) wsum[wv] = sc;
        __syncthreads();
        if (t < 8) {                                         // scan 8 wave sums
            int ws = wsum[t], s2 = ws;
#pragma unroll
            for (int off = 1; off < 8; off <<= 1) {
                int u = __shfl_up(s2, off, 8);
                if (t >= off) s2 += u;
            }
            wsum[t] = s2 - ws;                               // exclusive wave prefix
        }
        __syncthreads();
        int ex = gbase + (sc - c) + wsum[wv];                // excl. slot, node 2t
        cur[2 * t] = ex; cur[2 * t + 1] = ex + c0;
        int node = sl * FSLICE_NODES + 2 * t;
        if (node < N_NODES)     A.offsets[node]     = ex;
        if (node + 1 < N_NODES) A.offsets[node + 1] = ex + c0;
        __syncthreads();
        for (int i = t; i < n; i += THREADS) {
            unsigned int p = A.squeue[qb + i];
            int slot = atomicAdd(&cur[p >> 17], 1);          // LDS atomic
            A.csr_src[slot] = (int)(p & 0x1FFFFu);
        }
    }
    gridbar(A.bar);

    // ================= layers: [gather -> gemm] x 3 ==========================
    for (int l = 0; l < 3; ++l) {
        const ushort* Wt1 = A.Wt + (size_t)(2 * l) * D * D;
        const ushort* Wt2 = A.Wt + (size_t)(2 * l + 1) * D * D;
        const float* fold1 = A.folds + (size_t)(2 * l) * 2 * D;
        const float* fold2 = A.folds + (size_t)(2 * l + 1) * 2 * D;

        // ---- gather: buf0 -> buf1, wave-per-node, 16 outstanding row loads.
        // Pure phase: no LDS, no barriers -> 16 waves/CU issue continuously.
        {
            const unsigned int* base = (const unsigned int*)A.buf0;
            unsigned int* outb = (unsigned int*)A.buf1;
            int wid = bid * 8 + wv;
            for (int node = wid; node < N_NODES; node += GRID * 8) {
                unsigned int u = base[(size_t)node * 64 + lane];
                float ax = bflo(u), ay = bfhi(u);
                int b = A.offsets[node], e = A.offsets[node + 1];
                int i = b;
                for (; i + 15 < e; i += 16) {
                    int s0 = A.csr_src[i],      s1 = A.csr_src[i + 1],  s2 = A.csr_src[i + 2],  s3 = A.csr_src[i + 3];
                    int s4 = A.csr_src[i + 4],  s5 = A.csr_src[i + 5],  s6 = A.csr_src[i + 6],  s7 = A.csr_src[i + 7];
                    int s8 = A.csr_src[i + 8],  s9 = A.csr_src[i + 9],  sa = A.csr_src[i + 10], sb = A.csr_src[i + 11];
                    int sc = A.csr_src[i + 12], sd = A.csr_src[i + 13], se = A.csr_src[i + 14], sf = A.csr_src[i + 15];
                    unsigned int v0 = base[(size_t)s0 * 64 + lane];
                    unsigned int v1 = base[(size_t)s1 * 64 + lane];
                    unsigned int v2 = base[(size_t)s2 * 64 + lane];
                    unsigned int v3 = base[(size_t)s3 * 64 + lane];
                    unsigned int v4 = base[(size_t)s4 * 64 + lane];
                    unsigned int v5 = base[(size_t)s5 * 64 + lane];
                    unsigned int v6 = base[(size_t)s6 * 64 + lane];
                    unsigned int v7 = base[(size_t)s7 * 64 + lane];
                    unsigned int v8 = base[(size_t)s8 * 64 + lane];
                    unsigned int v9 = base[(size_t)s9 * 64 + lane];
                    unsigned int va = base[(size_t)sa * 64 + lane];
                    unsigned int vb = base[(size_t)sb * 64 + lane];
                    unsigned int vc = base[(size_t)sc * 64 + lane];
                    unsigned int vd = base[(size_t)sd * 64 + lane];
                    unsigned int ve = base[(size_t)se * 64 + lane];
                    unsigned int vf = base[(size_t)sf * 64 + lane];
                    ax += bflo(v0) + bflo(v1) + bflo(v2) + bflo(v3)
                        + bflo(v4) + bflo(v5) + bflo(v6) + bflo(v7)
                        + bflo(v8) + bflo(v9) + bflo(va) + bflo(vb)
                        + bflo(vc) + bflo(vd) + bflo(ve) + bflo(vf);
                    ay += bfhi(v0) + bfhi(v1) + bfhi(v2) + bfhi(v3)
                        + bfhi(v4) + bfhi(v5) + bfhi(v6) + bfhi(v7)
                        + bfhi(v8) + bfhi(v9) + bfhi(va) + bfhi(vb)
                        + bfhi(vc) + bfhi(vd) + bfhi(ve) + bfhi(vf);
                }
                for (; i + 3 < e; i += 4) {
                    int s0 = A.csr_src[i], s1 = A.csr_src[i + 1], s2 = A.csr_src[i + 2], s3 = A.csr_src[i + 3];
                    unsigned int v0 = base[(size_t)s0 * 64 + lane];
                    unsigned int v1 = base[(size_t)s1 * 64 + lane];
                    unsigned int v2 = base[(size_t)s2 * 64 + lane];
                    unsigned int v3 = base[(size_t)s3 * 64 + lane];
                    ax += bflo(v0) + bflo(v1) + bflo(v2) + bflo(v3);
                    ay += bfhi(v0) + bfhi(v1) + bfhi(v2) + bfhi(v3);
                }
                for (; i < e; ++i) {
                    unsigned int v = base[(size_t)A.csr_src[i] * 64 + lane];
                    ax += bflo(v); ay += bfhi(v);
                }
                outb[(size_t)node * 64 + lane] = packbf(ax, ay);
            }
        }
        gridbar(A.bar);

        // ---- gemm: buf1 -> buf0. 64-row tiles, 8 waves as (rb = wv&3, ch = wv>>2):
        // wave handles rows rb*16..+16, output cols ch*64..+64. Wave PAIRS share
        // rows -> extra barrier after A-frag loads before any H write.
        {
            ushort* As = (ushort*)smem;                      // 64*136*2 = 17408
            ushort* Bs = (ushort*)(smem + 17408);            // 128*136*2 = 34816
            const ushort* in = A.buf1;
            ushort* outp = A.buf0;
            int quad = lane >> 4, mr = lane & 15;
            int rb = wv & 3, ch = wv >> 2;
            int rbase = rb * 16;
            const uint4* w2v = (const uint4*)Wt2;
            for (int tile = bid; tile < N_TILES; tile += GRID) {
                int row0 = tile * 64;
#pragma unroll
                for (int i = 0; i < 2; ++i) {                // stage A (64x128)
                    int f = t + 512 * i; int m = f >> 4, g = f & 15;
                    *(float4*)(As + m * 136 + g * 8) =
                        *(const float4*)(in + (size_t)(row0 + m) * D + g * 8);
                }
#pragma unroll
                for (int i = 0; i < 4; ++i) {                // stage W1 (128x128)
                    int f = t + 512 * i; int m = f >> 4, g = f & 15;
                    *(float4*)(Bs + m * 136 + g * 8) =
                        *(const float4*)(Wt1 + (size_t)m * D + g * 8);
                }
                uint4 p0 = w2v[t];                           // W2 reg prefetch
                uint4 p1 = w2v[t + 512];
                uint4 p2 = w2v[t + 1024];
                uint4 p3 = w2v[t + 1536];
                __syncthreads();

                const ushort* ap = As + (rbase + mr) * 136 + quad * 8;
                bf16x8 a0 = *(const bf16x8*)(ap);
                bf16x8 a1 = *(const bf16x8*)(ap + 32);
                bf16x8 a2 = *(const bf16x8*)(ap + 64);
                bf16x8 a3 = *(const bf16x8*)(ap + 96);
                __syncthreads();    // pair wave must finish A-frag loads first

#pragma unroll
                for (int nt4 = 0; nt4 < 4; ++nt4) {          // GEMM1 + BN + relu
                    int nt = ch * 4 + nt4;
                    const ushort* bq = Bs + (nt * 16 + mr) * 136 + quad * 8;
                    bf16x8 b0 = *(const bf16x8*)(bq);
                    bf16x8 b1 = *(const bf16x8*)(bq + 32);
                    bf16x8 b2 = *(const bf16x8*)(bq + 64);
                    bf16x8 b3 = *(const bf16x8*)(bq + 96);
                    f32x4 acc = {0.f, 0.f, 0.f, 0.f};
                    acc = __builtin_amdgcn_mfma_f32_16x16x32_bf16(a0, b0, acc, 0, 0, 0);
                    acc = __builtin_amdgcn_mfma_f32_16x16x32_bf16(a1, b1, acc, 0, 0, 0);
                    acc = __builtin_amdgcn_mfma_f32_16x16x32_bf16(a2, b2, acc, 0, 0, 0);
                    acc = __builtin_amdgcn_mfma_f32_16x16x32_bf16(a3, b3, acc, 0, 0, 0);
                    int j = nt * 16 + mr;    // C/D: col=lane&15, row=quad*4+reg
                    float s = fold1[j], o = fold1[D + j];
#pragma unroll
                    for (int r = 0; r < 4; ++r) {
                        float z = fmaxf(fmaf(acc[r], s, o), 0.0f);
                        As[(rbase + quad * 4 + r) * 136 + j] = f2bf(z);
                    }
                }
                __syncthreads();    // all waves done with W1 + H fully written

                {                   // restage Bs with prefetched W2 (regs->LDS)
                    int f0 = t;        *(uint4*)(Bs + (f0 >> 4) * 136 + (f0 & 15) * 8) = p0;
                    int f1 = t + 512;  *(uint4*)(Bs + (f1 >> 4) * 136 + (f1 & 15) * 8) = p1;
                    int f2 = t + 1024; *(uint4*)(Bs + (f2 >> 4) * 136 + (f2 & 15) * 8) = p2;
                    int f3 = t + 1536; *(uint4*)(Bs + (f3 >> 4) * 136 + (f3 & 15) * 8) = p3;
                }
                const ushort* hp = As + (rbase + mr) * 136 + quad * 8;
                bf16x8 h0 = *(const bf16x8*)(hp);
                bf16x8 h1 = *(const bf16x8*)(hp + 32);
                bf16x8 h2 = *(const bf16x8*)(hp + 64);
                bf16x8 h3 = *(const bf16x8*)(hp + 96);
                __syncthreads();    // W2 staged; h-frags loaded before C writes

#pragma unroll
                for (int nt4 = 0; nt4 < 4; ++nt4) {          // GEMM2 + bias + relu
                    int nt = ch * 4 + nt4;
                    const ushort* bq = Bs + (nt * 16 + mr) * 136 + quad * 8;
                    bf16x8 b0 = *(const bf16x8*)(bq);
                    bf16x8 b1 = *(const bf16x8*)(bq + 32);
                    bf16x8 b2 = *(const bf16x8*)(bq + 64);
                    bf16x8 b3 = *(const bf16x8*)(bq + 96);
                    f32x4 acc = {0.f, 0.f, 0.f, 0.f};
                    acc = __builtin_amdgcn_mfma_f32_16x16x32_bf16(h0, b0, acc, 0, 0, 0);
                    acc = __builtin_amdgcn_mfma_f32_16x16x32_bf16(h1, b1, acc, 0, 0, 0);
                    acc = __builtin_amdgcn_mfma_f32_16x16x32_bf16(h2, b2, acc, 0, 0, 0);
                    acc = __builtin_amdgcn_mfma_f32_16x16x32_bf16(h3, b3, acc, 0, 0, 0);
                    int j = nt * 16 + mr;
                    float o = fold2[D + j];
#pragma unroll
                    for (int r = 0; r < 4; ++r) {
                        float z = fmaxf(acc[r] + o, 0.0f);
                        As[(rbase + quad * 4 + r) * 136 + j] = f2bf(z);
                    }
                }
                __syncthreads();

#pragma unroll
                for (int i = 0; i < 4; ++i) {                // coalesced copy-out
                    int f = t + 512 * i; int lr = f >> 5, g = f & 31;
                    if (row0 + lr < N_NODES)
                        *(float2*)(outp + (size_t)(row0 + lr) * D + g * 4) =
                            *(const float2*)(As + lr * 136 + g * 4);
                }
                __syncthreads();    // before next tile's stage overwrites As/Bs
            }
        }
        gridbar(A.bar);
    }

    // ================= phase 9: pool + head (4 graphs per block) =============
    if (bid < N_GRAPHS / 4) {
        float* row = (float*)smem;               // [4][128]
        float* t1  = (float*)smem + 512;         // [4][128]
        int sub = t >> 7, j = t & 127;
        int r = bid * 4 + sub;
        float acc = 0.0f;
        int b = A.gstart[r], e = A.gstart[r + 1];
        for (int i = b; i < e; ++i)
            acc += __uint_as_float(((unsigned int)A.buf0[(size_t)i * D + j]) << 16);
        row[sub * 128 + j] = acc;
        __syncthreads();
        float a1 = A.hb1[j];
        for (int k = 0; k < D; ++k) a1 = fmaf(row[sub * 128 + k], A.hW1[k * D + j], a1);
        t1[sub * 128 + j] = fmaxf(a1, 0.0f);
        __syncthreads();
        float a2 = A.hb2[j];
        for (int k = 0; k < D; ++k) a2 = fmaf(t1[sub * 128 + k], A.hW2[k * D + j], a2);
        A.out[r * D + j] = a2;
    }
}

// ---------------- launcher ----------------
extern "C" void kernel_launch(void* const* d_in, const int* in_sizes, int n_in,
                              void* d_out, int out_size, void* d_ws, size_t ws_size,
                              hipStream_t stream) {
    const int* ei = (const int*)d_in[1];

    char* ws = (char*)d_ws;
    size_t off = 0;
    auto alloc = [&](size_t bytes) -> void* {
        void* p = ws + off;
        off = (off + bytes + 255) & ~(size_t)255;
        return p;
    };
    const size_t NODE_BUF = (size_t)(N_NODES + 128) * D * sizeof(ushort);

    MegaArgs a;
    a.x       = (const float*)d_in[0];
    a.src     = ei;
    a.dst     = ei + N_EDGES;
    a.batch   = (const int*)d_in[2];
    a.W1      = (const float*)d_in[3];
    a.b1      = (const float*)d_in[4];
    a.gamma   = (const float*)d_in[5];
    a.beta    = (const float*)d_in[6];
    a.mean    = (const float*)d_in[7];
    a.var     = (const float*)d_in[8];
    a.W2      = (const float*)d_in[9];
    a.b2      = (const float*)d_in[10];
    a.hW1     = (const float*)d_in[11];
    a.hb1     = (const float*)d_in[12];
    a.hW2     = (const float*)d_in[13];
    a.hb2     = (const float*)d_in[14];
    a.out     = (float*)d_out;
    a.buf0    = (ushort*)alloc(NODE_BUF);
    a.buf1    = (ushort*)alloc(NODE_BUF);
    a.Wt      = (ushort*)alloc((size_t)6 * D * D * sizeof(ushort));
    a.folds   = (float*)alloc((size_t)6 * 2 * D * sizeof(float));
    a.squeue  = (unsigned int*)alloc((size_t)FNSLICE * FSLICE_CAP * sizeof(unsigned int));
    a.csr_src = (int*)alloc((size_t)(N_EDGES + 64) * sizeof(int));
    a.offsets = (int*)alloc((size_t)(N_NODES + 1) * sizeof(int));
    a.slice_tail = (int*)alloc((size_t)FNSLICE * sizeof(int));
    a.gstart  = (int*)alloc((size_t)(N_GRAPHS + 1) * sizeof(int));
    a.bar     = (unsigned int*)alloc(256);

    hipMemsetAsync(a.bar, 0, 256, stream);       // barrier state: count=0, gen=0
    gin_mega<<<GRID, THREADS, 0, stream>>>(a);
}

// Round 5
// 2067.465 us; speedup vs baseline: 1.3881x; 1.3881x over previous
//
#include <hip/hip_runtime.h>

#define N_NODES  100000
#define N_EDGES  1600000
#define N_GRAPHS 1024
#define D        128
#define BN_EPS   1e-5f

// --- geometry: 512 blocks x 512 thr = 2 blocks/CU, co-residency GUARANTEED
// (2 x 52224B LDS = 104KB <= 160KB; 16 waves <= 32; VGPR capped 128 via
// __launch_bounds__(512,4)). Normal launch + hand-rolled device-scope barrier.
#define GRID      512
#define THREADS   512
#define GTOT      (GRID * THREADS)          // 262144

// --- atomic-free CSR build geometry ---
#define FNSLICE      98                     // ceil(100000/1024) node slices
#define FSLICE_NODES 1024
#define FSLICE_CAP   20480                  // mean 16327, sigma~127
#define QCAP         64                     // per-block bin: mean 31.9 (+5.7σ)
#define CCHUNK       3125                   // 512*3125 == 1600000 exactly

// --- setup work ranges (grid-stride gtid) ---
#define CVT_ITEMS    1600000                // 100000*128/8
#define PW_ITEMS     98304                  // 6*128*128
#define FOLD_BASE    PW_ITEMS
#define GST_BASE     (PW_ITEMS + 768)

#define N_TILES      1563                   // ceil(100000/64)

typedef short bf16x8 __attribute__((ext_vector_type(8)));
typedef float f32x4  __attribute__((ext_vector_type(4)));

__device__ __forceinline__ ushort f2bf(float f) {        // RNE fp32->bf16
    unsigned int b = __float_as_uint(f);
    return (ushort)((b + 0x7fffu + ((b >> 16) & 1u)) >> 16);
}
__device__ __forceinline__ float bflo(unsigned int u) { return __uint_as_float(u << 16); }
__device__ __forceinline__ float bfhi(unsigned int u) { return __uint_as_float(u & 0xffff0000u); }
__device__ __forceinline__ unsigned int packbf(float x, float y) {
    return (unsigned int)f2bf(x) | ((unsigned int)f2bf(y) << 16);
}

struct MegaArgs {
    const float* x;
    const int*   src;
    const int*   dst;
    const int*   batch;
    const float* W1;  const float* b1;
    const float* gamma; const float* beta; const float* mean; const float* var;
    const float* W2;  const float* b2;
    const float* hW1; const float* hb1; const float* hW2; const float* hb2;
    float*       out;
    ushort*      buf0; ushort* buf1;
    ushort*      Wt;   float*  folds;
    unsigned int* squeue;
    int* csr_src; int* offsets; int* slice_tail; int* gstart;
    unsigned int* bar;          // [0]=arrival count, [1]=generation (memset 0)
};

// Sense-reversing grid barrier. R16 lesson: the spin MUST poll with a RELAXED
// agent atomic load. The previous ACQUIRE poll emitted buffer_inv (whole-L2
// invalidate) EVERY iteration from up to 511 spinning blocks -> millions of
// L2 invalidates destroyed the working set of blocks still computing
// (2813us, FETCH +35%, 3.4% VALU). A relaxed agent atomic load is a coherent
// load (sees remote release stores, no invalidate). The single post-loop
// __threadfence() by all threads provides the acquire exactly once.
__device__ __forceinline__ void gridbar(unsigned int* bar) {
    __threadfence();                        // release: write back dirty L2
    __syncthreads();                        // whole block fenced + arrived
    if (threadIdx.x == 0) {
        unsigned int g = __hip_atomic_load(&bar[1], __ATOMIC_RELAXED,
                                           __HIP_MEMORY_SCOPE_AGENT);
        unsigned int a = __hip_atomic_fetch_add(&bar[0], 1u, __ATOMIC_ACQ_REL,
                                                __HIP_MEMORY_SCOPE_AGENT);
        if (a == GRID - 1) {
            __hip_atomic_store(&bar[0], 0u, __ATOMIC_RELAXED,
                               __HIP_MEMORY_SCOPE_AGENT);
            __hip_atomic_store(&bar[1], g + 1u, __ATOMIC_RELEASE,
                               __HIP_MEMORY_SCOPE_AGENT);
        } else {
            while (__hip_atomic_load(&bar[1], __ATOMIC_RELAXED,
                                     __HIP_MEMORY_SCOPE_AGENT) == g)
                __builtin_amdgcn_s_sleep(16);
        }
    }
    __syncthreads();
    __threadfence();                        // acquire: invalidate stale caches
}

// Drain one CSR stream with the proven R11 16/4/1 ladder.
__device__ __forceinline__ void drain_stream(const unsigned int* __restrict__ base,
                                             const int* __restrict__ csr,
                                             int i, int e, int lane,
                                             float& ax, float& ay) {
    for (; i + 15 < e; i += 16) {
        int s0 = csr[i],      s1 = csr[i + 1],  s2 = csr[i + 2],  s3 = csr[i + 3];
        int s4 = csr[i + 4],  s5 = csr[i + 5],  s6 = csr[i + 6],  s7 = csr[i + 7];
        int s8 = csr[i + 8],  s9 = csr[i + 9],  sa = csr[i + 10], sb = csr[i + 11];
        int sc = csr[i + 12], sd = csr[i + 13], se = csr[i + 14], sf = csr[i + 15];
        unsigned int v0 = base[(size_t)s0 * 64 + lane];
        unsigned int v1 = base[(size_t)s1 * 64 + lane];
        unsigned int v2 = base[(size_t)s2 * 64 + lane];
        unsigned int v3 = base[(size_t)s3 * 64 + lane];
        unsigned int v4 = base[(size_t)s4 * 64 + lane];
        unsigned int v5 = base[(size_t)s5 * 64 + lane];
        unsigned int v6 = base[(size_t)s6 * 64 + lane];
        unsigned int v7 = base[(size_t)s7 * 64 + lane];
        unsigned int v8 = base[(size_t)s8 * 64 + lane];
        unsigned int v9 = base[(size_t)s9 * 64 + lane];
        unsigned int va = base[(size_t)sa * 64 + lane];
        unsigned int vb = base[(size_t)sb * 64 + lane];
        unsigned int vc = base[(size_t)sc * 64 + lane];
        unsigned int vd = base[(size_t)sd * 64 + lane];
        unsigned int ve = base[(size_t)se * 64 + lane];
        unsigned int vf = base[(size_t)sf * 64 + lane];
        ax += bflo(v0) + bflo(v1) + bflo(v2) + bflo(v3)
            + bflo(v4) + bflo(v5) + bflo(v6) + bflo(v7)
            + bflo(v8) + bflo(v9) + bflo(va) + bflo(vb)
            + bflo(vc) + bflo(vd) + bflo(ve) + bflo(vf);
        ay += bfhi(v0) + bfhi(v1) + bfhi(v2) + bfhi(v3)
            + bfhi(v4) + bfhi(v5) + bfhi(v6) + bfhi(v7)
            + bfhi(v8) + bfhi(v9) + bfhi(va) + bfhi(vb)
            + bfhi(vc) + bfhi(vd) + bfhi(ve) + bfhi(vf);
    }
    for (; i + 3 < e; i += 4) {
        int s0 = csr[i], s1 = csr[i + 1], s2 = csr[i + 2], s3 = csr[i + 3];
        unsigned int v0 = base[(size_t)s0 * 64 + lane];
        unsigned int v1 = base[(size_t)s1 * 64 + lane];
        unsigned int v2 = base[(size_t)s2 * 64 + lane];
        unsigned int v3 = base[(size_t)s3 * 64 + lane];
        ax += bflo(v0) + bflo(v1) + bflo(v2) + bflo(v3);
        ay += bfhi(v0) + bfhi(v1) + bfhi(v2) + bfhi(v3);
    }
    for (; i < e; ++i) {
        unsigned int v = base[(size_t)csr[i] * 64 + lane];
        ax += bflo(v); ay += bfhi(v);
    }
}

// One kernel, phases separated by gridbar():
//   [compact+setup] -> fill -> [gather -> gemm]x3 -> pool   (8 barriers)
__global__ __launch_bounds__(THREADS, 4) void gin_mega(MegaArgs A) {
    __shared__ __align__(16) char smem[52224];   // phase-aliased union

    const int t    = threadIdx.x;
    const int bid  = blockIdx.x;
    const int gtid = bid * THREADS + t;
    const int lane = t & 63, wv = t >> 6;        // 8 waves/block

    // ================= phase 0a: compact (bin edges by 1024-node slice) ======
    // Independent of setup (reads only src/dst; slice_tail zeroed by memset).
    {
        unsigned int* qbuf = (unsigned int*)smem;            // 98*64*4 = 25088
        int* qcnt  = (int*)(smem + 25088);                   // 98
        int* qbase = (int*)(smem + 25480);                   // 98
        if (t < FNSLICE) qcnt[t] = 0;
        __syncthreads();
        int e0 = bid * CCHUNK;
        int eend = e0 + CCHUNK;
        for (int e = e0 + t; e < eend; e += THREADS) {
            int d = A.dst[e], s = A.src[e];
            int sl = d >> 10;
            unsigned int pk = ((unsigned int)(d & 1023) << 17) | (unsigned int)s;
            int pos = atomicAdd(&qcnt[sl], 1);
            if (pos < QCAP) qbuf[sl * QCAP + pos] = pk;
            else {  // rare by construction: direct spill, still correct
                int gp = atomicAdd(&A.slice_tail[sl], 1);
                A.squeue[(size_t)sl * FSLICE_CAP + gp] = pk;
            }
        }
        __syncthreads();
        if (t < FNSLICE) {
            int n = qcnt[t]; if (n > QCAP) n = QCAP;
            qbase[t] = atomicAdd(&A.slice_tail[t], n);
        }
        __syncthreads();
        for (int sl = wv; sl < FNSLICE; sl += 8) {
            int n = qcnt[sl]; if (n > QCAP) n = QCAP;
            int gb = qbase[sl];
            for (int i = lane; i < n; i += 64)
                A.squeue[(size_t)sl * FSLICE_CAP + gb + i] = qbuf[sl * QCAP + i];
        }
    }

    // ================= phase 0b: setup (cvt + W^T + folds + gstart) ==========
    for (int i = gtid; i < CVT_ITEMS; i += GTOT) {           // x -> bf16
        size_t p = (size_t)i * 8;
        float4 v0 = *(const float4*)(A.x + p);
        float4 v1 = *(const float4*)(A.x + p + 4);
        uint4 o;
        o.x = packbf(v0.x, v0.y); o.y = packbf(v0.z, v0.w);
        o.z = packbf(v1.x, v1.y); o.w = packbf(v1.z, v1.w);
        *(uint4*)(A.buf0 + p) = o;
    }
    if (gtid < PW_ITEMS) {                                   // W -> bf16 transposed
        int i = gtid >> 14, r = gtid & 16383;
        int n = r >> 7, k = r & 127, l = i >> 1;
        const float* W = (i & 1) ? (A.W2 + (size_t)l * D * D) : (A.W1 + (size_t)l * D * D);
        A.Wt[gtid] = f2bf(W[k * D + n]);
    }
    {
        int fi = gtid - FOLD_BASE;                           // BN folds
        if (fi >= 0 && fi < 6 * D) {
            int i = fi >> 7, j = fi & 127, l = i >> 1;
            float s, o;
            if ((i & 1) == 0) {
                float sv = A.gamma[l * D + j] * rsqrtf(A.var[l * D + j] + BN_EPS);
                s = sv;
                o = (A.b1[l * D + j] - A.mean[l * D + j]) * sv + A.beta[l * D + j];
            } else {
                s = 1.0f;
                o = A.b2[l * D + j];
            }
            A.folds[(size_t)i * 2 * D + j]     = s;
            A.folds[(size_t)i * 2 * D + D + j] = o;
        }
        int gi = gtid - GST_BASE;                            // gstart binary search
        if (gi >= 0 && gi <= N_GRAPHS) {
            int lo = 0, hi = N_NODES;
            while (lo < hi) {
                int mid = (lo + hi) >> 1;
                if (A.batch[mid] < gi) lo = mid + 1; else hi = mid;
            }
            A.gstart[gi] = lo;
        }
        if (gtid == GST_BASE + N_GRAPHS + 1) A.offsets[N_NODES] = N_EDGES;
    }
    gridbar(A.bar);

    // ================= phase 1: fill (per-slice hist -> scan -> scatter) =====
    if (bid < FNSLICE) {
        int* hist  = (int*)smem;                             // 1024
        int* cur   = (int*)(smem + 4096);                    // 1024
        int* sbase = (int*)(smem + 8192);                    // 128
        int* wsum  = (int*)(smem + 8704);                    // 8
        int sl = bid;
        int n = A.slice_tail[sl];
        if (t < 128) sbase[t] = (t < FNSLICE) ? A.slice_tail[t] : 0;
        hist[t] = 0; hist[t + 512] = 0;
        __syncthreads();
        for (int off = 1; off < 128; off <<= 1) {            // scan slice totals
            int u = (t < 128 && t >= off) ? sbase[t - off] : 0;
            __syncthreads();
            if (t < 128) sbase[t] += u;
            __syncthreads();
        }
        int gbase = (sl == 0) ? 0 : sbase[sl - 1];
        size_t qb = (size_t)sl * FSLICE_CAP;
        for (int i = t; i < n; i += THREADS)
            atomicAdd(&hist[A.squeue[qb + i] >> 17], 1);
        __syncthreads();
        int c0 = hist[2 * t], c1 = hist[2 * t + 1], c = c0 + c1;
        int sc = c;
#pragma unroll
        for (int off = 1; off < 64; off <<= 1) {             // wave-inclusive scan
            int u = __shfl_up(sc, off, 64);
            if (lane >= off) sc += u;
        }
        if (lane == 63) wsum[wv] = sc;
        __syncthreads();
        if (t < 8) {                                         // scan 8 wave sums
            int ws = wsum[t], s2 = ws;
#pragma unroll
            for (int off = 1; off < 8; off <<= 1) {
                int u = __shfl_up(s2, off, 8);
                if (t >= off) s2 += u;
            }
            wsum[t] = s2 - ws;                               // exclusive wave prefix
        }
        __syncthreads();
        int ex = gbase + (sc - c) + wsum[wv];                // excl. slot, node 2t
        cur[2 * t] = ex; cur[2 * t + 1] = ex + c0;
        int node = sl * FSLICE_NODES + 2 * t;
        if (node < N_NODES)     A.offsets[node]     = ex;
        if (node + 1 < N_NODES) A.offsets[node + 1] = ex + c0;
        __syncthreads();
        for (int i = t; i < n; i += THREADS) {
            unsigned int p = A.squeue[qb + i];
            int slot = atomicAdd(&cur[p >> 17], 1);          // LDS atomic
            A.csr_src[slot] = (int)(p & 0x1FFFFu);
        }
    }
    gridbar(A.bar);

    // ================= layers: [gather -> gemm] x 3 ==========================
    for (int l = 0; l < 3; ++l) {
        const ushort* Wt1 = A.Wt + (size_t)(2 * l) * D * D;
        const ushort* Wt2 = A.Wt + (size_t)(2 * l + 1) * D * D;
        const float* fold1 = A.folds + (size_t)(2 * l) * 2 * D;
        const float* fold2 = A.folds + (size_t)(2 * l + 1) * 2 * D;

        // ---- gather: buf0 -> buf1. DUAL-STREAM: each wave aggregates a node
        // PAIR with an interleaved dual-8 ladder (R13 data: rate ∝ waves ×
        // outstanding; at 16 waves/CU vs R0's 21, sustaining ~16 outstanding
        // beats R0's ~10 average from the single-node ladder ramp-down).
        {
            const unsigned int* base = (const unsigned int*)A.buf0;
            unsigned int* outb = (unsigned int*)A.buf1;
            int wid = bid * 8 + wv;                          // 4096 waves
            for (int p = wid; 2 * p < N_NODES; p += GRID * 8) {
                int n0 = 2 * p;                              // n1 = n0+1 < 100000
                unsigned int u0 = base[(size_t)n0 * 64 + lane];
                unsigned int u1 = base[(size_t)(n0 + 1) * 64 + lane];
                float ax0 = bflo(u0), ay0 = bfhi(u0);
                float ax1 = bflo(u1), ay1 = bfhi(u1);
                int i0 = A.offsets[n0];
                int e0 = A.offsets[n0 + 1];
                int i1 = e0;                                 // offsets[n1] == e0
                int e1 = A.offsets[n0 + 2];
                while (i0 + 7 < e0 && i1 + 7 < e1) {         // dual-8: 16 in flight
                    int s0 = A.csr_src[i0],     s1 = A.csr_src[i0 + 1],
                        s2 = A.csr_src[i0 + 2], s3 = A.csr_src[i0 + 3];
                    int s4 = A.csr_src[i0 + 4], s5 = A.csr_src[i0 + 5],
                        s6 = A.csr_src[i0 + 6], s7 = A.csr_src[i0 + 7];
                    int r0 = A.csr_src[i1],     r1 = A.csr_src[i1 + 1],
                        r2 = A.csr_src[i1 + 2], r3 = A.csr_src[i1 + 3];
                    int r4 = A.csr_src[i1 + 4], r5 = A.csr_src[i1 + 5],
                        r6 = A.csr_src[i1 + 6], r7 = A.csr_src[i1 + 7];
                    unsigned int v0 = base[(size_t)s0 * 64 + lane];
                    unsigned int v1 = base[(size_t)s1 * 64 + lane];
                    unsigned int v2 = base[(size_t)s2 * 64 + lane];
                    unsigned int v3 = base[(size_t)s3 * 64 + lane];
                    unsigned int v4 = base[(size_t)s4 * 64 + lane];
                    unsigned int v5 = base[(size_t)s5 * 64 + lane];
                    unsigned int v6 = base[(size_t)s6 * 64 + lane];
                    unsigned int v7 = base[(size_t)s7 * 64 + lane];
                    unsigned int w0 = base[(size_t)r0 * 64 + lane];
                    unsigned int w1 = base[(size_t)r1 * 64 + lane];
                    unsigned int w2 = base[(size_t)r2 * 64 + lane];
                    unsigned int w3 = base[(size_t)r3 * 64 + lane];
                    unsigned int w4 = base[(size_t)r4 * 64 + lane];
                    unsigned int w5 = base[(size_t)r5 * 64 + lane];
                    unsigned int w6 = base[(size_t)r6 * 64 + lane];
                    unsigned int w7 = base[(size_t)r7 * 64 + lane];
                    ax0 += bflo(v0) + bflo(v1) + bflo(v2) + bflo(v3)
                         + bflo(v4) + bflo(v5) + bflo(v6) + bflo(v7);
                    ay0 += bfhi(v0) + bfhi(v1) + bfhi(v2) + bfhi(v3)
                         + bfhi(v4) + bfhi(v5) + bfhi(v6) + bfhi(v7);
                    ax1 += bflo(w0) + bflo(w1) + bflo(w2) + bflo(w3)
                         + bflo(w4) + bflo(w5) + bflo(w6) + bflo(w7);
                    ay1 += bfhi(w0) + bfhi(w1) + bfhi(w2) + bfhi(w3)
                         + bfhi(w4) + bfhi(w5) + bfhi(w6) + bfhi(w7);
                    i0 += 8; i1 += 8;
                }
                drain_stream(base, A.csr_src, i0, e0, lane, ax0, ay0);
                drain_stream(base, A.csr_src, i1, e1, lane, ax1, ay1);
                outb[(size_t)n0 * 64 + lane]       = packbf(ax0, ay0);
                outb[(size_t)(n0 + 1) * 64 + lane] = packbf(ax1, ay1);
            }
        }
        gridbar(A.bar);

        // ---- gemm: buf1 -> buf0. 64-row tiles, 8 waves as (rb = wv&3, ch = wv>>2).
        {
            ushort* As = (ushort*)smem;                      // 64*136*2 = 17408
            ushort* Bs = (ushort*)(smem + 17408);            // 128*136*2 = 34816
            const ushort* in = A.buf1;
            ushort* outp = A.buf0;
            int quad = lane >> 4, mr = lane & 15;
            int rb = wv & 3, ch = wv >> 2;
            int rbase = rb * 16;
            const uint4* w2v = (const uint4*)Wt2;
            for (int tile = bid; tile < N_TILES; tile += GRID) {
                int row0 = tile * 64;
#pragma unroll
                for (int i = 0; i < 2; ++i) {                // stage A (64x128)
                    int f = t + 512 * i; int m = f >> 4, g = f & 15;
                    *(float4*)(As + m * 136 + g * 8) =
                        *(const float4*)(in + (size_t)(row0 + m) * D + g * 8);
                }
#pragma unroll
                for (int i = 0; i < 4; ++i) {                // stage W1 (128x128)
                    int f = t + 512 * i; int m = f >> 4, g = f & 15;
                    *(float4*)(Bs + m * 136 + g * 8) =
                        *(const float4*)(Wt1 + (size_t)m * D + g * 8);
                }
                uint4 p0 = w2v[t];                           // W2 reg prefetch
                uint4 p1 = w2v[t + 512];
                uint4 p2 = w2v[t + 1024];
                uint4 p3 = w2v[t + 1536];
                __syncthreads();

                const ushort* ap = As + (rbase + mr) * 136 + quad * 8;
                bf16x8 a0 = *(const bf16x8*)(ap);
                bf16x8 a1 = *(const bf16x8*)(ap + 32);
                bf16x8 a2 = *(const bf16x8*)(ap + 64);
                bf16x8 a3 = *(const bf16x8*)(ap + 96);
                __syncthreads();    // pair wave must finish A-frag loads first

#pragma unroll
                for (int nt4 = 0; nt4 < 4; ++nt4) {          // GEMM1 + BN + relu
                    int nt = ch * 4 + nt4;
                    const ushort* bq = Bs + (nt * 16 + mr) * 136 + quad * 8;
                    bf16x8 b0 = *(const bf16x8*)(bq);
                    bf16x8 b1 = *(const bf16x8*)(bq + 32);
                    bf16x8 b2 = *(const bf16x8*)(bq + 64);
                    bf16x8 b3 = *(const bf16x8*)(bq + 96);
                    f32x4 acc = {0.f, 0.f, 0.f, 0.f};
                    acc = __builtin_amdgcn_mfma_f32_16x16x32_bf16(a0, b0, acc, 0, 0, 0);
                    acc = __builtin_amdgcn_mfma_f32_16x16x32_bf16(a1, b1, acc, 0, 0, 0);
                    acc = __builtin_amdgcn_mfma_f32_16x16x32_bf16(a2, b2, acc, 0, 0, 0);
                    acc = __builtin_amdgcn_mfma_f32_16x16x32_bf16(a3, b3, acc, 0, 0, 0);
                    int j = nt * 16 + mr;    // C/D: col=lane&15, row=quad*4+reg
                    float s = fold1[j], o = fold1[D + j];
#pragma unroll
                    for (int r = 0; r < 4; ++r) {
                        float z = fmaxf(fmaf(acc[r], s, o), 0.0f);
                        As[(rbase + quad * 4 + r) * 136 + j] = f2bf(z);
                    }
                }
                __syncthreads();    // all waves done with W1 + H fully written

                {                   // restage Bs with prefetched W2 (regs->LDS)
                    int f0 = t;        *(uint4*)(Bs + (f0 >> 4) * 136 + (f0 & 15) * 8) = p0;
                    int f1 = t + 512;  *(uint4*)(Bs + (f1 >> 4) * 136 + (f1 & 15) * 8) = p1;
                    int f2 = t + 1024; *(uint4*)(Bs + (f2 >> 4) * 136 + (f2 & 15) * 8) = p2;
                    int f3 = t + 1536; *(uint4*)(Bs + (f3 >> 4) * 136 + (f3 & 15) * 8) = p3;
                }
                const ushort* hp = As + (rbase + mr) * 136 + quad * 8;
                bf16x8 h0 = *(const bf16x8*)(hp);
                bf16x8 h1 = *(const bf16x8*)(hp + 32);
                bf16x8 h2 = *(const bf16x8*)(hp + 64);
                bf16x8 h3 = *(const bf16x8*)(hp + 96);
                __syncthreads();    // W2 staged; h-frags loaded before C writes

#pragma unroll
                for (int nt4 = 0; nt4 < 4; ++nt4) {          // GEMM2 + bias + relu
                    int nt = ch * 4 + nt4;
                    const ushort* bq = Bs + (nt * 16 + mr) * 136 + quad * 8;
                    bf16x8 b0 = *(const bf16x8*)(bq);
                    bf16x8 b1 = *(const bf16x8*)(bq + 32);
                    bf16x8 b2 = *(const bf16x8*)(bq + 64);
                    bf16x8 b3 = *(const bf16x8*)(bq + 96);
                    f32x4 acc = {0.f, 0.f, 0.f, 0.f};
                    acc = __builtin_amdgcn_mfma_f32_16x16x32_bf16(h0, b0, acc, 0, 0, 0);
                    acc = __builtin_amdgcn_mfma_f32_16x16x32_bf16(h1, b1, acc, 0, 0, 0);
                    acc = __builtin_amdgcn_mfma_f32_16x16x32_bf16(h2, b2, acc, 0, 0, 0);
                    acc = __builtin_amdgcn_mfma_f32_16x16x32_bf16(h3, b3, acc, 0, 0, 0);
                    int j = nt * 16 + mr;
                    float o = fold2[D + j];
#pragma unroll
                    for (int r = 0; r < 4; ++r) {
                        float z = fmaxf(acc[r] + o, 0.0f);
                        As[(rbase + quad * 4 + r) * 136 + j] = f2bf(z);
                    }
                }
                __syncthreads();

#pragma unroll
                for (int i = 0; i < 4; ++i) {                // coalesced copy-out
                    int f = t + 512 * i; int lr = f >> 5, g = f & 31;
                    if (row0 + lr < N_NODES)
                        *(float2*)(outp + (size_t)(row0 + lr) * D + g * 4) =
                            *(const float2*)(As + lr * 136 + g * 4);
                }
                __syncthreads();    // before next tile's stage overwrites As/Bs
            }
        }
        gridbar(A.bar);
    }

    // ================= phase 8: pool + head (4 graphs per block) =============
    if (bid < N_GRAPHS / 4) {
        float* row = (float*)smem;               // [4][128]
        float* t1  = (float*)smem + 512;         // [4][128]
        int sub = t >> 7, j = t & 127;
        int r = bid * 4 + sub;
        float acc = 0.0f;
        int b = A.gstart[r], e = A.gstart[r + 1];
        for (int i = b; i < e; ++i)
            acc += __uint_as_float(((unsigned int)A.buf0[(size_t)i * D + j]) << 16);
        row[sub * 128 + j] = acc;
        __syncthreads();
        float a1 = A.hb1[j];
        for (int k = 0; k < D; ++k) a1 = fmaf(row[sub * 128 + k], A.hW1[k * D + j], a1);
        t1[sub * 128 + j] = fmaxf(a1, 0.0f);
        __syncthreads();
        float a2 = A.hb2[j];
        for (int k = 0; k < D; ++k) a2 = fmaf(t1[sub * 128 + k], A.hW2[k * D + j], a2);
        A.out[r * D + j] = a2;
    }
}

// ---------------- launcher ----------------
extern "C" void kernel_launch(void* const* d_in, const int* in_sizes, int n_in,
                              void* d_out, int out_size, void* d_ws, size_t ws_size,
                              hipStream_t stream) {
    const int* ei = (const int*)d_in[1];

    char* ws = (char*)d_ws;
    size_t off = 0;
    auto alloc = [&](size_t bytes) -> void* {
        void* p = ws + off;
        off = (off + bytes + 255) & ~(size_t)255;
        return p;
    };
    const size_t NODE_BUF = (size_t)(N_NODES + 128) * D * sizeof(ushort);

    MegaArgs a;
    a.x       = (const float*)d_in[0];
    a.src     = ei;
    a.dst     = ei + N_EDGES;
    a.batch   = (const int*)d_in[2];
    a.W1      = (const float*)d_in[3];
    a.b1      = (const float*)d_in[4];
    a.gamma   = (const float*)d_in[5];
    a.beta    = (const float*)d_in[6];
    a.mean    = (const float*)d_in[7];
    a.var     = (const float*)d_in[8];
    a.W2      = (const float*)d_in[9];
    a.b2      = (const float*)d_in[10];
    a.hW1     = (const float*)d_in[11];
    a.hb1     = (const float*)d_in[12];
    a.hW2     = (const float*)d_in[13];
    a.hb2     = (const float*)d_in[14];
    a.out     = (float*)d_out;
    a.buf0    = (ushort*)alloc(NODE_BUF);
    a.buf1    = (ushort*)alloc(NODE_BUF);
    a.Wt      = (ushort*)alloc((size_t)6 * D * D * sizeof(ushort));
    a.folds   = (float*)alloc((size_t)6 * 2 * D * sizeof(float));
    a.squeue  = (unsigned int*)alloc((size_t)FNSLICE * FSLICE_CAP * sizeof(unsigned int));
    a.csr_src = (int*)alloc((size_t)(N_EDGES + 64) * sizeof(int));
    a.offsets = (int*)alloc((size_t)(N_NODES + 1) * sizeof(int));
    a.slice_tail = (int*)alloc((size_t)FNSLICE * sizeof(int));
    a.gstart  = (int*)alloc((size_t)(N_GRAPHS + 1) * sizeof(int));
    a.bar     = (unsigned int*)alloc(256);

    hipMemsetAsync(a.slice_tail, 0, FNSLICE * sizeof(int), stream);
    hipMemsetAsync(a.bar, 0, 256, stream);       // barrier: count=0, gen=0
    gin_mega<<<GRID, THREADS, 0, stream>>>(a);
}

// Round 6
// 439.644 us; speedup vs baseline: 6.5276x; 4.7026x over previous
//
#include <hip/hip_runtime.h>

#define N_NODES  100000
#define N_EDGES  1600000
#define N_GRAPHS 1024
#define D        128
#define BN_EPS   1e-5f

// --- atomic-free CSR build geometry ---
#define FNSLICE      98                  // ceil(100000/1024) node slices
#define FSLICE_NODES 1024                // nodes per slice (d>>10)
#define FSLICE_CAP   20480               // queue cap: mean 16384, sigma~127
#define QCAP         96                  // per-block LDS bin: mean 41, +12 sigma
#define CCHUNK       4000
#define CGRID        400                 // 400*4000 == N_EDGES

// --- setup_kernel block ranges (256 thr each); compact merged in (R18) ---
#define CVT_BLOCKS   6250                // 100000*128 / (256*8)
#define PW_BLOCKS    384                 // 6*128*128 / 256
#define FOLD_BLOCKS  3                   // 6*128 / 256
#define GST_BLOCKS   5                   // 1025 / 256
#define MISC_BASE    (CVT_BLOCKS + PW_BLOCKS + FOLD_BLOCKS + GST_BLOCKS)
#define COMPACT_BASE (MISC_BASE + 1)
#define SETUP_GRID   (COMPACT_BASE + CGRID)

#define GATHER_GRID  12500               // 12500 blk * 4 waves * 2 nodes = 100000

typedef short bf16x8 __attribute__((ext_vector_type(8)));
typedef float f32x4  __attribute__((ext_vector_type(4)));

__device__ __forceinline__ ushort f2bf(float f) {        // RNE fp32->bf16
    unsigned int b = __float_as_uint(f);
    return (ushort)((b + 0x7fffu + ((b >> 16) & 1u)) >> 16);
}
__device__ __forceinline__ float bflo(unsigned int u) { return __uint_as_float(u << 16); }
__device__ __forceinline__ float bfhi(unsigned int u) { return __uint_as_float(u & 0xffff0000u); }
__device__ __forceinline__ unsigned int packbf(float x, float y) {
    return (unsigned int)f2bf(x) | ((unsigned int)f2bf(y) << 16);
}

// ---------------- setup: cvt_x + prep_w + folds + gstart + misc + COMPACT ----
// R18: the CSR pass-1 (edge binning) is independent of every other setup range
// (reads only src/dst; slice_tail pre-zeroed by hipMemsetAsync), so it rides
// in the same launch as extra blocks -> one less launch boundary.
__global__ __launch_bounds__(256) void setup_kernel(
        const float* __restrict__ x, ushort* __restrict__ xb,
        const float* __restrict__ W1, const float* __restrict__ W2,
        ushort* __restrict__ Wt,
        const float* __restrict__ b1, const float* __restrict__ gamma,
        const float* __restrict__ beta, const float* __restrict__ mean,
        const float* __restrict__ var, const float* __restrict__ b2,
        float* __restrict__ folds,
        const int* __restrict__ batch, int* __restrict__ gstart,
        int* __restrict__ slice_tail, int* __restrict__ offsets,
        const int* __restrict__ src, const int* __restrict__ dst,
        unsigned int* __restrict__ squeue) {
    __shared__ unsigned int qbuf[FNSLICE * QCAP];   // 37.6 KB (compact range)
    __shared__ int qcnt[FNSLICE];
    __shared__ int qbase[FNSLICE];
    int b = blockIdx.x, t = threadIdx.x;
    if (b < CVT_BLOCKS) {                                  // x -> bf16
        size_t i = ((size_t)b * 256 + t) * 8;
        float4 v0 = *(const float4*)(x + i);
        float4 v1 = *(const float4*)(x + i + 4);
        uint4 o;
        o.x = packbf(v0.x, v0.y); o.y = packbf(v0.z, v0.w);
        o.z = packbf(v1.x, v1.y); o.w = packbf(v1.z, v1.w);
        *(uint4*)(xb + i) = o;
    } else if (b < CVT_BLOCKS + PW_BLOCKS) {               // W -> bf16 transposed
        int idx = (b - CVT_BLOCKS) * 256 + t;              // [0, 6*16384)
        int i = idx >> 14, r = idx & 16383;
        int n = r >> 7, k = r & 127, l = i >> 1;
        const float* W = (i & 1) ? (W2 + (size_t)l * D * D) : (W1 + (size_t)l * D * D);
        Wt[idx] = f2bf(W[k * D + n]);
    } else if (b < CVT_BLOCKS + PW_BLOCKS + FOLD_BLOCKS) { // BN folds
        int idx = (b - CVT_BLOCKS - PW_BLOCKS) * 256 + t;  // [0, 768)
        if (idx < 6 * D) {
            int i = idx >> 7, j = idx & 127, l = i >> 1;
            float s, o;
            if ((i & 1) == 0) {
                float sv = gamma[l * D + j] * rsqrtf(var[l * D + j] + BN_EPS);
                s = sv;
                o = (b1[l * D + j] - mean[l * D + j]) * sv + beta[l * D + j];
            } else {
                s = 1.0f;
                o = b2[l * D + j];
            }
            folds[(size_t)i * 2 * D + j]     = s;
            folds[(size_t)i * 2 * D + D + j] = o;
        }
    } else if (b < MISC_BASE) {                            // gstart
        int g = (b - CVT_BLOCKS - PW_BLOCKS - FOLD_BLOCKS) * 256 + t;
        if (g <= N_GRAPHS) {
            int lo = 0, hi = N_NODES;
            while (lo < hi) {
                int mid = (lo + hi) >> 1;
                if (batch[mid] < g) lo = mid + 1; else hi = mid;
            }
            gstart[g] = lo;
        }
    } else if (b == MISC_BASE) {                           // misc
        if (t == 255) offsets[N_NODES] = N_EDGES;
    } else {                                               // compact (CSR pass 1)
        for (int i = t; i < FNSLICE; i += 256) qcnt[i] = 0;
        __syncthreads();
        int e0 = (b - COMPACT_BASE) * CCHUNK;
        int eend = e0 + CCHUNK; if (eend > N_EDGES) eend = N_EDGES;
        for (int e = e0 + t; e < eend; e += 256) {
            int d = dst[e], s = src[e];
            int sl = d >> 10;
            unsigned int pk = ((unsigned int)(d & 1023) << 17) | (unsigned int)s;
            int pos = atomicAdd(&qcnt[sl], 1);
            if (pos < QCAP) qbuf[sl * QCAP + pos] = pk;
            else {  // ~never (12-sigma): direct spill, still correct
                int gp = atomicAdd(&slice_tail[sl], 1);
                squeue[(size_t)sl * FSLICE_CAP + gp] = pk;
            }
        }
        __syncthreads();
        for (int i = t; i < FNSLICE; i += 256) {
            int n = qcnt[i]; if (n > QCAP) n = QCAP;
            qbase[i] = atomicAdd(&slice_tail[i], n);
        }
        __syncthreads();
        int wv = t >> 6, ln = t & 63;
        for (int sl = wv; sl < FNSLICE; sl += 4) {
            int n = qcnt[sl]; if (n > QCAP) n = QCAP;
            int gb = qbase[sl];
            for (int i = ln; i < n; i += 64)
                squeue[(size_t)sl * FSLICE_CAP + gb + i] = qbuf[sl * QCAP + i];
        }
    }
}

// ---------------- CSR pass 2: per-slice hist -> scan -> fill, LDS atomics only ----------------
__global__ __launch_bounds__(1024) void fill_local(const unsigned int* __restrict__ squeue,
                                                   const int* __restrict__ slice_tail,
                                                   int* __restrict__ offsets,
                                                   int* __restrict__ csr_src) {
    __shared__ int hist[FSLICE_NODES];
    __shared__ int cur[FSLICE_NODES];
    __shared__ int sbase[128];
    __shared__ int wsum[16];
    int sl = blockIdx.x, t = threadIdx.x;
    int n = slice_tail[sl];
    if (t < 128) sbase[t] = (t < FNSLICE) ? slice_tail[t] : 0;
    hist[t] = 0;
    __syncthreads();
    for (int off = 1; off < 128; off <<= 1) {      // in-block scan of slice totals
        int u = (t < 128 && t >= off) ? sbase[t - off] : 0;
        __syncthreads();
        if (t < 128) sbase[t] += u;
        __syncthreads();
    }
    int gbase = (sl == 0) ? 0 : sbase[sl - 1];
    size_t qb = (size_t)sl * FSLICE_CAP;
    for (int i = t; i < n; i += 1024)
        atomicAdd(&hist[squeue[qb + i] >> 17], 1);
    __syncthreads();
    int c = hist[t];
    int lane = t & 63, w = t >> 6;
    int sc = c;
#pragma unroll
    for (int off = 1; off < 64; off <<= 1) {       // wave-inclusive scan
        int u = __shfl_up(sc, off, 64);
        if (lane >= off) sc += u;
    }
    if (lane == 63) wsum[w] = sc;
    __syncthreads();
    if (t < 16) {                                  // scan the 16 wave sums
        int ws = wsum[t];
        int s2 = ws;
#pragma unroll
        for (int off = 1; off < 16; off <<= 1) {
            int u = __shfl_up(s2, off, 16);
            if (t >= off) s2 += u;
        }
        wsum[t] = s2 - ws;                         // exclusive wave prefix
    }
    __syncthreads();
    int gslot = gbase + sc + wsum[w] - c;          // global exclusive slot
    cur[t] = gslot;
    int node = sl * FSLICE_NODES + t;
    if (node < N_NODES) offsets[node] = gslot;
    __syncthreads();
    for (int i = t; i < n; i += 1024) {
        unsigned int p = squeue[qb + i];
        int slot = atomicAdd(&cur[p >> 17], 1);    // LDS atomic
        csr_src[slot] = (int)(p & 0x1FFFFu);
    }
}

// Drain one CSR stream with the proven R11 16/4/1 ladder.
__device__ __forceinline__ void drain_stream(const unsigned int* __restrict__ base,
                                             const int* __restrict__ csr,
                                             int i, int e, int lane,
                                             float& ax, float& ay) {
    for (; i + 15 < e; i += 16) {
        int s0 = csr[i],      s1 = csr[i + 1],  s2 = csr[i + 2],  s3 = csr[i + 3];
        int s4 = csr[i + 4],  s5 = csr[i + 5],  s6 = csr[i + 6],  s7 = csr[i + 7];
        int s8 = csr[i + 8],  s9 = csr[i + 9],  sa = csr[i + 10], sb = csr[i + 11];
        int sc = csr[i + 12], sd = csr[i + 13], se = csr[i + 14], sf = csr[i + 15];
        unsigned int v0 = base[(size_t)s0 * 64 + lane];
        unsigned int v1 = base[(size_t)s1 * 64 + lane];
        unsigned int v2 = base[(size_t)s2 * 64 + lane];
        unsigned int v3 = base[(size_t)s3 * 64 + lane];
        unsigned int v4 = base[(size_t)s4 * 64 + lane];
        unsigned int v5 = base[(size_t)s5 * 64 + lane];
        unsigned int v6 = base[(size_t)s6 * 64 + lane];
        unsigned int v7 = base[(size_t)s7 * 64 + lane];
        unsigned int v8 = base[(size_t)s8 * 64 + lane];
        unsigned int v9 = base[(size_t)s9 * 64 + lane];
        unsigned int va = base[(size_t)sa * 64 + lane];
        unsigned int vb = base[(size_t)sb * 64 + lane];
        unsigned int vc = base[(size_t)sc * 64 + lane];
        unsigned int vd = base[(size_t)sd * 64 + lane];
        unsigned int ve = base[(size_t)se * 64 + lane];
        unsigned int vf = base[(size_t)sf * 64 + lane];
        ax += bflo(v0) + bflo(v1) + bflo(v2) + bflo(v3)
            + bflo(v4) + bflo(v5) + bflo(v6) + bflo(v7)
            + bflo(v8) + bflo(v9) + bflo(va) + bflo(vb)
            + bflo(vc) + bflo(vd) + bflo(ve) + bflo(vf);
        ay += bfhi(v0) + bfhi(v1) + bfhi(v2) + bfhi(v3)
            + bfhi(v4) + bfhi(v5) + bfhi(v6) + bfhi(v7)
            + bfhi(v8) + bfhi(v9) + bfhi(va) + bfhi(vb)
            + bfhi(vc) + bfhi(vd) + bfhi(ve) + bfhi(vf);
    }
    for (; i + 3 < e; i += 4) {
        int s0 = csr[i], s1 = csr[i + 1], s2 = csr[i + 2], s3 = csr[i + 3];
        unsigned int v0 = base[(size_t)s0 * 64 + lane];
        unsigned int v1 = base[(size_t)s1 * 64 + lane];
        unsigned int v2 = base[(size_t)s2 * 64 + lane];
        unsigned int v3 = base[(size_t)s3 * 64 + lane];
        ax += bflo(v0) + bflo(v1) + bflo(v2) + bflo(v3);
        ay += bfhi(v0) + bfhi(v1) + bfhi(v2) + bfhi(v3);
    }
    for (; i < e; ++i) {
        unsigned int v = base[(size_t)csr[i] * 64 + lane];
        ax += bflo(v); ay += bfhi(v);
    }
}

// ---------------- aggregation: DUAL-STREAM (R18) ----------------
// R13/R17 measured gather BW ∝ issuing-wave count => it's in the
// latency×concurrency regime. The single-node R11 ladder averages only ~10
// outstanding loads (mean degree 16: one 16-deep pass, then 4/1 drains).
// Each wave now aggregates a node PAIR with an interleaved dual-8 ladder:
// ~16 outstanding sustained, same loads, same layout. Imbalanced pairs fall
// back to the proven 16/4/1 ladder on the longer stream (drain_stream).
__global__ __launch_bounds__(256) void gather_bf16(const ushort* __restrict__ xb,
                                                   const int* __restrict__ offsets,
                                                   const int* __restrict__ csr_src,
                                                   ushort* __restrict__ hb) {
    int wv = threadIdx.x >> 6, lane = threadIdx.x & 63;
    int n0 = (blockIdx.x * 4 + wv) * 2;       // 12500*4*2 == N_NODES
    const unsigned int* base = (const unsigned int*)xb;
    unsigned int u0 = base[(size_t)n0 * 64 + lane];
    unsigned int u1 = base[(size_t)(n0 + 1) * 64 + lane];
    float ax0 = bflo(u0), ay0 = bfhi(u0);
    float ax1 = bflo(u1), ay1 = bfhi(u1);
    int i0 = offsets[n0];
    int e0 = offsets[n0 + 1];
    int i1 = e0;                              // CSR contiguity: offsets[n0+1]
    int e1 = offsets[n0 + 2];
    while (i0 + 7 < e0 && i1 + 7 < e1) {      // dual-8: 16 loads in flight
        int s0 = csr_src[i0],     s1 = csr_src[i0 + 1],
            s2 = csr_src[i0 + 2], s3 = csr_src[i0 + 3];
        int s4 = csr_src[i0 + 4], s5 = csr_src[i0 + 5],
            s6 = csr_src[i0 + 6], s7 = csr_src[i0 + 7];
        int r0 = csr_src[i1],     r1 = csr_src[i1 + 1],
            r2 = csr_src[i1 + 2], r3 = csr_src[i1 + 3];
        int r4 = csr_src[i1 + 4], r5 = csr_src[i1 + 5],
            r6 = csr_src[i1 + 6], r7 = csr_src[i1 + 7];
        unsigned int v0 = base[(size_t)s0 * 64 + lane];
        unsigned int v1 = base[(size_t)s1 * 64 + lane];
        unsigned int v2 = base[(size_t)s2 * 64 + lane];
        unsigned int v3 = base[(size_t)s3 * 64 + lane];
        unsigned int v4 = base[(size_t)s4 * 64 + lane];
        unsigned int v5 = base[(size_t)s5 * 64 + lane];
        unsigned int v6 = base[(size_t)s6 * 64 + lane];
        unsigned int v7 = base[(size_t)s7 * 64 + lane];
        unsigned int w0 = base[(size_t)r0 * 64 + lane];
        unsigned int w1 = base[(size_t)r1 * 64 + lane];
        unsigned int w2 = base[(size_t)r2 * 64 + lane];
        unsigned int w3 = base[(size_t)r3 * 64 + lane];
        unsigned int w4 = base[(size_t)r4 * 64 + lane];
        unsigned int w5 = base[(size_t)r5 * 64 + lane];
        unsigned int w6 = base[(size_t)r6 * 64 + lane];
        unsigned int w7 = base[(size_t)r7 * 64 + lane];
        ax0 += bflo(v0) + bflo(v1) + bflo(v2) + bflo(v3)
             + bflo(v4) + bflo(v5) + bflo(v6) + bflo(v7);
        ay0 += bfhi(v0) + bfhi(v1) + bfhi(v2) + bfhi(v3)
             + bfhi(v4) + bfhi(v5) + bfhi(v6) + bfhi(v7);
        ax1 += bflo(w0) + bflo(w1) + bflo(w2) + bflo(w3)
             + bflo(w4) + bflo(w5) + bflo(w6) + bflo(w7);
        ay1 += bfhi(w0) + bfhi(w1) + bfhi(w2) + bfhi(w3)
             + bfhi(w4) + bfhi(w5) + bfhi(w6) + bfhi(w7);
        i0 += 8; i1 += 8;
    }
    drain_stream(base, csr_src, i0, e0, lane, ax0, ay0);
    drain_stream(base, csr_src, i1, e1, lane, ax1, ay1);
    ((unsigned int*)hb)[(size_t)n0 * 64 + lane]       = packbf(ax0, ay0);
    ((unsigned int*)hb)[(size_t)(n0 + 1) * 64 + lane] = packbf(ax1, ay1);
}

// ---------------- fused layer: out = relu(relu(BN(in@W1))@W2 + b2) ----------------
// R9 structure + W2 register prefetch (proven R0 kernel, unchanged).
__global__ __launch_bounds__(512, 4) void fused_gemm(const ushort* __restrict__ in,
                                                     ushort* __restrict__ out,
                                                     const ushort* __restrict__ Wt1,
                                                     const ushort* __restrict__ Wt2,
                                                     const float* __restrict__ fold1,
                                                     const float* __restrict__ fold2) {
    __shared__ ushort As[128 * 136];    // A tile -> H tile -> C tile (aliased)
    __shared__ ushort Bs[128 * 136];    // W1^T, then W2^T
    int t = threadIdx.x;
    int row0 = blockIdx.x * 128;        // 782 blocks, last partial (32 rows)

#pragma unroll
    for (int i = 0; i < 4; ++i) {       // stage A + W1
        int f = t + 512 * i; int m = f >> 4, g = f & 15;
        *(float4*)(As + m * 136 + g * 8) = *(const float4*)(in + (size_t)(row0 + m) * D + g * 8);
        *(float4*)(Bs + m * 136 + g * 8) = *(const float4*)(Wt1 + (size_t)m * D + g * 8);
    }
    // W2 prefetch into registers (consumed at restage, after gemm1)
    const uint4* w2v = (const uint4*)Wt2;
    uint4 p0 = w2v[t];
    uint4 p1 = w2v[t + 512];
    uint4 p2 = w2v[t + 1024];
    uint4 p3 = w2v[t + 1536];
    __syncthreads();

    int lane = t & 63, wv = t >> 6;
    int quad = lane >> 4, mr = lane & 15;
    int mbase = wv * 16;
    const ushort* ap = As + (mbase + mr) * 136 + quad * 8;
    bf16x8 a0 = *(const bf16x8*)(ap);
    bf16x8 a1 = *(const bf16x8*)(ap + 32);
    bf16x8 a2 = *(const bf16x8*)(ap + 64);
    bf16x8 a3 = *(const bf16x8*)(ap + 96);

    // --- GEMM1: H = relu(BN(A@W1)) -> As own rows (in-wave DS ordering: safe)
#pragma unroll
    for (int nt = 0; nt < 8; ++nt) {
        const ushort* bq = Bs + (nt * 16 + mr) * 136 + quad * 8;
        bf16x8 b0 = *(const bf16x8*)(bq);
        bf16x8 b1 = *(const bf16x8*)(bq + 32);
        bf16x8 b2 = *(const bf16x8*)(bq + 64);
        bf16x8 b3 = *(const bf16x8*)(bq + 96);
        f32x4 acc = {0.f, 0.f, 0.f, 0.f};
        acc = __builtin_amdgcn_mfma_f32_16x16x32_bf16(a0, b0, acc, 0, 0, 0);
        acc = __builtin_amdgcn_mfma_f32_16x16x32_bf16(a1, b1, acc, 0, 0, 0);
        acc = __builtin_amdgcn_mfma_f32_16x16x32_bf16(a2, b2, acc, 0, 0, 0);
        acc = __builtin_amdgcn_mfma_f32_16x16x32_bf16(a3, b3, acc, 0, 0, 0);
        int j = nt * 16 + mr;           // C/D: col=lane&15, row=quad*4+reg (m89)
        float s = fold1[j], o = fold1[D + j];
#pragma unroll
        for (int r = 0; r < 4; ++r) {
            float z = fmaxf(fmaf(acc[r], s, o), 0.0f);
            As[(mbase + quad * 4 + r) * 136 + j] = f2bf(z);
        }
    }
    __syncthreads();                    // all waves done reading W1 from Bs

    {                                   // restage Bs with prefetched W2 (regs->LDS)
        int f0 = t;          *(uint4*)(Bs + (f0 >> 4) * 136 + (f0 & 15) * 8) = p0;
        int f1 = t + 512;    *(uint4*)(Bs + (f1 >> 4) * 136 + (f1 & 15) * 8) = p1;
        int f2 = t + 1024;   *(uint4*)(Bs + (f2 >> 4) * 136 + (f2 & 15) * 8) = p2;
        int f3 = t + 1536;   *(uint4*)(Bs + (f3 >> 4) * 136 + (f3 & 15) * 8) = p3;
    }
    const ushort* hp = As + (mbase + mr) * 136 + quad * 8;
    bf16x8 h0 = *(const bf16x8*)(hp);
    bf16x8 h1 = *(const bf16x8*)(hp + 32);
    bf16x8 h2 = *(const bf16x8*)(hp + 64);
    bf16x8 h3 = *(const bf16x8*)(hp + 96);
    __syncthreads();                    // W2 staged

    // --- GEMM2: C = relu(H@W2 + b2) -> As own rows
#pragma unroll
    for (int nt = 0; nt < 8; ++nt) {
        const ushort* bq = Bs + (nt * 16 + mr) * 136 + quad * 8;
        bf16x8 b0 = *(const bf16x8*)(bq);
        bf16x8 b1 = *(const bf16x8*)(bq + 32);
        bf16x8 b2 = *(const bf16x8*)(bq + 64);
        bf16x8 b3 = *(const bf16x8*)(bq + 96);
        f32x4 acc = {0.f, 0.f, 0.f, 0.f};
        acc = __builtin_amdgcn_mfma_f32_16x16x32_bf16(h0, b0, acc, 0, 0, 0);
        acc = __builtin_amdgcn_mfma_f32_16x16x32_bf16(h1, b1, acc, 0, 0, 0);
        acc = __builtin_amdgcn_mfma_f32_16x16x32_bf16(h2, b2, acc, 0, 0, 0);
        acc = __builtin_amdgcn_mfma_f32_16x16x32_bf16(h3, b3, acc, 0, 0, 0);
        int j = nt * 16 + mr;
        float o = fold2[D + j];
#pragma unroll
        for (int r = 0; r < 4; ++r) {
            float z = fmaxf(acc[r] + o, 0.0f);
            As[(mbase + quad * 4 + r) * 136 + j] = f2bf(z);
        }
    }
    __syncthreads();

#pragma unroll
    for (int i = 0; i < 8; ++i) {       // coalesced copy-out, float2 = 4 bf16
        int f = t + 512 * i; int lr = f >> 5, g = f & 31;
        if (row0 + lr < N_NODES)
            *(float2*)(out + (size_t)(row0 + lr) * D + g * 4) =
                *(const float2*)(As + lr * 136 + g * 4);
    }
}

// ---------------- pooling + head fused: out[r] = relu(pool(r)@W1+b1)@W2+b2 ----------------
__global__ __launch_bounds__(128) void poolhead_kernel(const ushort* __restrict__ xb,
                                                       const int* __restrict__ gstart,
                                                       const float* __restrict__ W1,
                                                       const float* __restrict__ b1,
                                                       const float* __restrict__ W2,
                                                       const float* __restrict__ b2,
                                                       float* __restrict__ out) {
    __shared__ float row[128];
    __shared__ float t1[128];
    int r = blockIdx.x, j = threadIdx.x;
    float acc = 0.0f;
    int b = gstart[r], e = gstart[r + 1];
    for (int i = b; i < e; ++i)
        acc += __uint_as_float(((unsigned int)xb[(size_t)i * D + j]) << 16);
    row[j] = acc;
    __syncthreads();
    float a1 = b1[j];
    for (int k = 0; k < D; ++k) a1 = fmaf(row[k], W1[k * D + j], a1);
    t1[j] = fmaxf(a1, 0.0f);
    __syncthreads();
    float a2 = b2[j];
    for (int k = 0; k < D; ++k) a2 = fmaf(t1[k], W2[k * D + j], a2);
    out[r * D + j] = a2;
}

// ---------------- launcher ----------------
extern "C" void kernel_launch(void* const* d_in, const int* in_sizes, int n_in,
                              void* d_out, int out_size, void* d_ws, size_t ws_size,
                              hipStream_t stream) {
    const float* x        = (const float*)d_in[0];
    const int*   ei       = (const int*)d_in[1];
    const int*   src      = ei;
    const int*   dst      = ei + N_EDGES;
    const int*   batch    = (const int*)d_in[2];
    const float* conv_W1  = (const float*)d_in[3];
    const float* conv_b1  = (const float*)d_in[4];
    const float* bn_gamma = (const float*)d_in[5];
    const float* bn_beta  = (const float*)d_in[6];
    const float* bn_mean  = (const float*)d_in[7];
    const float* bn_var   = (const float*)d_in[8];
    const float* conv_W2  = (const float*)d_in[9];
    const float* conv_b2  = (const float*)d_in[10];
    const float* head_W1  = (const float*)d_in[11];
    const float* head_b1  = (const float*)d_in[12];
    const float* head_W2  = (const float*)d_in[13];
    const float* head_b2  = (const float*)d_in[14];
    float* out = (float*)d_out;

    char* ws = (char*)d_ws;
    size_t off = 0;
    auto alloc = [&](size_t bytes) -> void* {
        void* p = ws + off;
        off = (off + bytes + 255) & ~(size_t)255;
        return p;
    };
    const size_t NODE_BUF = (size_t)(N_NODES + 128) * D * sizeof(ushort);
    ushort* buf0    = (ushort*)alloc(NODE_BUF);
    ushort* buf1    = (ushort*)alloc(NODE_BUF);
    ushort* Wt      = (ushort*)alloc((size_t)6 * D * D * sizeof(ushort));
    float*  folds   = (float*)alloc((size_t)6 * 2 * D * sizeof(float));
    unsigned int* squeue = (unsigned int*)alloc((size_t)FNSLICE * FSLICE_CAP * sizeof(unsigned int));
    int*   csr_src  = (int*)alloc((size_t)(N_EDGES + 64) * sizeof(int));
    int*   offsets  = (int*)alloc((size_t)(N_NODES + 1) * sizeof(int));
    int*   slice_tail = (int*)alloc((size_t)FNSLICE * sizeof(int));
    int*   gstart   = (int*)alloc((size_t)(N_GRAPHS + 1) * sizeof(int));

    hipMemsetAsync(slice_tail, 0, FNSLICE * sizeof(int), stream);
    setup_kernel<<<SETUP_GRID, 256, 0, stream>>>(
        x, buf0, conv_W1, conv_W2, Wt,
        conv_b1, bn_gamma, bn_beta, bn_mean, bn_var, conv_b2, folds,
        batch, gstart, slice_tail, offsets, src, dst, squeue);
    fill_local<<<FNSLICE, 1024, 0, stream>>>(squeue, slice_tail, offsets, csr_src);

    const int FUSED_GRID = (N_NODES + 127) / 128;   // 782
    for (int l = 0; l < 3; ++l) {
        gather_bf16<<<GATHER_GRID, 256, 0, stream>>>(buf0, offsets, csr_src, buf1);
        fused_gemm<<<FUSED_GRID, 512, 0, stream>>>(buf1, buf0,
            Wt + (size_t)(2 * l) * D * D, Wt + (size_t)(2 * l + 1) * D * D,
            folds + (size_t)(2 * l) * 2 * D, folds + (size_t)(2 * l + 1) * 2 * D);
    }

    poolhead_kernel<<<N_GRAPHS, 128, 0, stream>>>(buf0, gstart, head_W1, head_b1,
                                                  head_W2, head_b2, out);
}

// Round 7
// 411.422 us; speedup vs baseline: 6.9753x; 1.0686x over previous
//
#include <hip/hip_runtime.h>

#define N_NODES  100000
#define N_EDGES  1600000
#define N_GRAPHS 1024
#define D        128
#define BN_EPS   1e-5f

// --- atomic-free CSR build geometry ---
#define FNSLICE      98                  // ceil(100000/1024) node slices
#define FSLICE_NODES 1024                // nodes per slice (d>>10)
#define FSLICE_CAP   20480               // queue cap: mean 16384, sigma~127
#define QCAP         96                  // per-block LDS bin: mean 41, +12 sigma
#define CCHUNK       4000
#define CGRID        400                 // 400*4000 == N_EDGES

// --- setup_kernel block ranges (256 thr each); compact merged (R18),
// pool-zero merged (R19, replaces the gstart range: pool-fused epilogue
// reads batch[] directly, gstart no longer needed) ---
#define CVT_BLOCKS   6250                // 100000*128 / (256*8)
#define PW_BLOCKS    384                 // 6*128*128 / 256
#define FOLD_BLOCKS  3                   // 6*128 / 256
#define PZ_BLOCKS    128                 // 1024*128 floats / (256*4/float4)
#define PZ_BASE      (CVT_BLOCKS + PW_BLOCKS + FOLD_BLOCKS)
#define MISC_BASE    (PZ_BASE + PZ_BLOCKS)
#define COMPACT_BASE (MISC_BASE + 1)
#define SETUP_GRID   (COMPACT_BASE + CGRID)

#define GATHER_GRID  12500               // 12500 blk * 4 waves * 2 nodes = 100000

typedef short bf16x8 __attribute__((ext_vector_type(8)));
typedef float f32x4  __attribute__((ext_vector_type(4)));

__device__ __forceinline__ ushort f2bf(float f) {        // RNE fp32->bf16
    unsigned int b = __float_as_uint(f);
    return (ushort)((b + 0x7fffu + ((b >> 16) & 1u)) >> 16);
}
__device__ __forceinline__ float bflo(unsigned int u) { return __uint_as_float(u << 16); }
__device__ __forceinline__ float bfhi(unsigned int u) { return __uint_as_float(u & 0xffff0000u); }
__device__ __forceinline__ unsigned int packbf(float x, float y) {
    return (unsigned int)f2bf(x) | ((unsigned int)f2bf(y) << 16);
}

// ---------------- setup: cvt_x + prep_w + folds + pool-zero + misc + compact ----
__global__ __launch_bounds__(256) void setup_kernel(
        const float* __restrict__ x, ushort* __restrict__ xb,
        const float* __restrict__ W1, const float* __restrict__ W2,
        ushort* __restrict__ Wt,
        const float* __restrict__ b1, const float* __restrict__ gamma,
        const float* __restrict__ beta, const float* __restrict__ mean,
        const float* __restrict__ var, const float* __restrict__ b2,
        float* __restrict__ folds, float* __restrict__ pool,
        int* __restrict__ slice_tail, int* __restrict__ offsets,
        const int* __restrict__ src, const int* __restrict__ dst,
        unsigned int* __restrict__ squeue) {
    __shared__ unsigned int qbuf[FNSLICE * QCAP];   // 37.6 KB (compact range)
    __shared__ int qcnt[FNSLICE];
    __shared__ int qbase[FNSLICE];
    int b = blockIdx.x, t = threadIdx.x;
    if (b < CVT_BLOCKS) {                                  // x -> bf16
        size_t i = ((size_t)b * 256 + t) * 8;
        float4 v0 = *(const float4*)(x + i);
        float4 v1 = *(const float4*)(x + i + 4);
        uint4 o;
        o.x = packbf(v0.x, v0.y); o.y = packbf(v0.z, v0.w);
        o.z = packbf(v1.x, v1.y); o.w = packbf(v1.z, v1.w);
        *(uint4*)(xb + i) = o;
    } else if (b < CVT_BLOCKS + PW_BLOCKS) {               // W -> bf16 transposed
        int idx = (b - CVT_BLOCKS) * 256 + t;              // [0, 6*16384)
        int i = idx >> 14, r = idx & 16383;
        int n = r >> 7, k = r & 127, l = i >> 1;
        const float* W = (i & 1) ? (W2 + (size_t)l * D * D) : (W1 + (size_t)l * D * D);
        Wt[idx] = f2bf(W[k * D + n]);
    } else if (b < PZ_BASE) {                              // BN folds
        int idx = (b - CVT_BLOCKS - PW_BLOCKS) * 256 + t;  // [0, 768)
        if (idx < 6 * D) {
            int i = idx >> 7, j = idx & 127, l = i >> 1;
            float s, o;
            if ((i & 1) == 0) {
                float sv = gamma[l * D + j] * rsqrtf(var[l * D + j] + BN_EPS);
                s = sv;
                o = (b1[l * D + j] - mean[l * D + j]) * sv + beta[l * D + j];
            } else {
                s = 1.0f;
                o = b2[l * D + j];
            }
            folds[(size_t)i * 2 * D + j]     = s;
            folds[(size_t)i * 2 * D + D + j] = o;
        }
    } else if (b < MISC_BASE) {                            // pool-zero (512KB)
        int idx = (b - PZ_BASE) * 256 + t;                 // [0, 32768) float4s
        ((float4*)pool)[idx] = float4{0.f, 0.f, 0.f, 0.f};
    } else if (b == MISC_BASE) {                           // misc
        if (t == 255) offsets[N_NODES] = N_EDGES;
    } else {                                               // compact (CSR pass 1)
        for (int i = t; i < FNSLICE; i += 256) qcnt[i] = 0;
        __syncthreads();
        int e0 = (b - COMPACT_BASE) * CCHUNK;
        int eend = e0 + CCHUNK; if (eend > N_EDGES) eend = N_EDGES;
        for (int e = e0 + t; e < eend; e += 256) {
            int d = dst[e], s = src[e];
            int sl = d >> 10;
            unsigned int pk = ((unsigned int)(d & 1023) << 17) | (unsigned int)s;
            int pos = atomicAdd(&qcnt[sl], 1);
            if (pos < QCAP) qbuf[sl * QCAP + pos] = pk;
            else {  // ~never (12-sigma): direct spill, still correct
                int gp = atomicAdd(&slice_tail[sl], 1);
                squeue[(size_t)sl * FSLICE_CAP + gp] = pk;
            }
        }
        __syncthreads();
        for (int i = t; i < FNSLICE; i += 256) {
            int n = qcnt[i]; if (n > QCAP) n = QCAP;
            qbase[i] = atomicAdd(&slice_tail[i], n);
        }
        __syncthreads();
        int wv = t >> 6, ln = t & 63;
        for (int sl = wv; sl < FNSLICE; sl += 4) {
            int n = qcnt[sl]; if (n > QCAP) n = QCAP;
            int gb = qbase[sl];
            for (int i = ln; i < n; i += 64)
                squeue[(size_t)sl * FSLICE_CAP + gb + i] = qbuf[sl * QCAP + i];
        }
    }
}

// ---------------- CSR pass 2: per-slice hist -> scan -> fill, LDS atomics only ----------------
__global__ __launch_bounds__(1024) void fill_local(const unsigned int* __restrict__ squeue,
                                                   const int* __restrict__ slice_tail,
                                                   int* __restrict__ offsets,
                                                   int* __restrict__ csr_src) {
    __shared__ int hist[FSLICE_NODES];
    __shared__ int cur[FSLICE_NODES];
    __shared__ int sbase[128];
    __shared__ int wsum[16];
    int sl = blockIdx.x, t = threadIdx.x;
    int n = slice_tail[sl];
    if (t < 128) sbase[t] = (t < FNSLICE) ? slice_tail[t] : 0;
    hist[t] = 0;
    __syncthreads();
    for (int off = 1; off < 128; off <<= 1) {      // in-block scan of slice totals
        int u = (t < 128 && t >= off) ? sbase[t - off] : 0;
        __syncthreads();
        if (t < 128) sbase[t] += u;
        __syncthreads();
    }
    int gbase = (sl == 0) ? 0 : sbase[sl - 1];
    size_t qb = (size_t)sl * FSLICE_CAP;
    for (int i = t; i < n; i += 1024)
        atomicAdd(&hist[squeue[qb + i] >> 17], 1);
    __syncthreads();
    int c = hist[t];
    int lane = t & 63, w = t >> 6;
    int sc = c;
#pragma unroll
    for (int off = 1; off < 64; off <<= 1) {       // wave-inclusive scan
        int u = __shfl_up(sc, off, 64);
        if (lane >= off) sc += u;
    }
    if (lane == 63) wsum[w] = sc;
    __syncthreads();
    if (t < 16) {                                  // scan the 16 wave sums
        int ws = wsum[t];
        int s2 = ws;
#pragma unroll
        for (int off = 1; off < 16; off <<= 1) {
            int u = __shfl_up(s2, off, 16);
            if (t >= off) s2 += u;
        }
        wsum[t] = s2 - ws;                         // exclusive wave prefix
    }
    __syncthreads();
    int gslot = gbase + sc + wsum[w] - c;          // global exclusive slot
    cur[t] = gslot;
    int node = sl * FSLICE_NODES + t;
    if (node < N_NODES) offsets[node] = gslot;
    __syncthreads();
    for (int i = t; i < n; i += 1024) {
        unsigned int p = squeue[qb + i];
        int slot = atomicAdd(&cur[p >> 17], 1);    // LDS atomic
        csr_src[slot] = (int)(p & 0x1FFFFu);
    }
}

// Drain one CSR stream with the proven R11 16/4/1 ladder.
__device__ __forceinline__ void drain_stream(const unsigned int* __restrict__ base,
                                             const int* __restrict__ csr,
                                             int i, int e, int lane,
                                             float& ax, float& ay) {
    for (; i + 15 < e; i += 16) {
        int s0 = csr[i],      s1 = csr[i + 1],  s2 = csr[i + 2],  s3 = csr[i + 3];
        int s4 = csr[i + 4],  s5 = csr[i + 5],  s6 = csr[i + 6],  s7 = csr[i + 7];
        int s8 = csr[i + 8],  s9 = csr[i + 9],  sa = csr[i + 10], sb = csr[i + 11];
        int sc = csr[i + 12], sd = csr[i + 13], se = csr[i + 14], sf = csr[i + 15];
        unsigned int v0 = base[(size_t)s0 * 64 + lane];
        unsigned int v1 = base[(size_t)s1 * 64 + lane];
        unsigned int v2 = base[(size_t)s2 * 64 + lane];
        unsigned int v3 = base[(size_t)s3 * 64 + lane];
        unsigned int v4 = base[(size_t)s4 * 64 + lane];
        unsigned int v5 = base[(size_t)s5 * 64 + lane];
        unsigned int v6 = base[(size_t)s6 * 64 + lane];
        unsigned int v7 = base[(size_t)s7 * 64 + lane];
        unsigned int v8 = base[(size_t)s8 * 64 + lane];
        unsigned int v9 = base[(size_t)s9 * 64 + lane];
        unsigned int va = base[(size_t)sa * 64 + lane];
        unsigned int vb = base[(size_t)sb * 64 + lane];
        unsigned int vc = base[(size_t)sc * 64 + lane];
        unsigned int vd = base[(size_t)sd * 64 + lane];
        unsigned int ve = base[(size_t)se * 64 + lane];
        unsigned int vf = base[(size_t)sf * 64 + lane];
        ax += bflo(v0) + bflo(v1) + bflo(v2) + bflo(v3)
            + bflo(v4) + bflo(v5) + bflo(v6) + bflo(v7)
            + bflo(v8) + bflo(v9) + bflo(va) + bflo(vb)
            + bflo(vc) + bflo(vd) + bflo(ve) + bflo(vf);
        ay += bfhi(v0) + bfhi(v1) + bfhi(v2) + bfhi(v3)
            + bfhi(v4) + bfhi(v5) + bfhi(v6) + bfhi(v7)
            + bfhi(v8) + bfhi(v9) + bfhi(va) + bfhi(vb)
            + bfhi(vc) + bfhi(vd) + bfhi(ve) + bfhi(vf);
    }
    for (; i + 3 < e; i += 4) {
        int s0 = csr[i], s1 = csr[i + 1], s2 = csr[i + 2], s3 = csr[i + 3];
        unsigned int v0 = base[(size_t)s0 * 64 + lane];
        unsigned int v1 = base[(size_t)s1 * 64 + lane];
        unsigned int v2 = base[(size_t)s2 * 64 + lane];
        unsigned int v3 = base[(size_t)s3 * 64 + lane];
        ax += bflo(v0) + bflo(v1) + bflo(v2) + bflo(v3);
        ay += bfhi(v0) + bfhi(v1) + bfhi(v2) + bfhi(v3);
    }
    for (; i < e; ++i) {
        unsigned int v = base[(size_t)csr[i] * 64 + lane];
        ax += bflo(v); ay += bfhi(v);
    }
}

// ---------------- aggregation: dual-stream (R18; kept — marginally better, and
// R12/R18 nulls prove the random-row path saturates ~3.5 TB/s: do not re-tune).
__global__ __launch_bounds__(256) void gather_bf16(const ushort* __restrict__ xb,
                                                   const int* __restrict__ offsets,
                                                   const int* __restrict__ csr_src,
                                                   ushort* __restrict__ hb) {
    int wv = threadIdx.x >> 6, lane = threadIdx.x & 63;
    int n0 = (blockIdx.x * 4 + wv) * 2;       // 12500*4*2 == N_NODES
    const unsigned int* base = (const unsigned int*)xb;
    unsigned int u0 = base[(size_t)n0 * 64 + lane];
    unsigned int u1 = base[(size_t)(n0 + 1) * 64 + lane];
    float ax0 = bflo(u0), ay0 = bfhi(u0);
    float ax1 = bflo(u1), ay1 = bfhi(u1);
    int i0 = offsets[n0];
    int e0 = offsets[n0 + 1];
    int i1 = e0;                              // CSR contiguity: offsets[n0+1]
    int e1 = offsets[n0 + 2];
    while (i0 + 7 < e0 && i1 + 7 < e1) {      // dual-8: 16 loads in flight
        int s0 = csr_src[i0],     s1 = csr_src[i0 + 1],
            s2 = csr_src[i0 + 2], s3 = csr_src[i0 + 3];
        int s4 = csr_src[i0 + 4], s5 = csr_src[i0 + 5],
            s6 = csr_src[i0 + 6], s7 = csr_src[i0 + 7];
        int r0 = csr_src[i1],     r1 = csr_src[i1 + 1],
            r2 = csr_src[i1 + 2], r3 = csr_src[i1 + 3];
        int r4 = csr_src[i1 + 4], r5 = csr_src[i1 + 5],
            r6 = csr_src[i1 + 6], r7 = csr_src[i1 + 7];
        unsigned int v0 = base[(size_t)s0 * 64 + lane];
        unsigned int v1 = base[(size_t)s1 * 64 + lane];
        unsigned int v2 = base[(size_t)s2 * 64 + lane];
        unsigned int v3 = base[(size_t)s3 * 64 + lane];
        unsigned int v4 = base[(size_t)s4 * 64 + lane];
        unsigned int v5 = base[(size_t)s5 * 64 + lane];
        unsigned int v6 = base[(size_t)s6 * 64 + lane];
        unsigned int v7 = base[(size_t)s7 * 64 + lane];
        unsigned int w0 = base[(size_t)r0 * 64 + lane];
        unsigned int w1 = base[(size_t)r1 * 64 + lane];
        unsigned int w2 = base[(size_t)r2 * 64 + lane];
        unsigned int w3 = base[(size_t)r3 * 64 + lane];
        unsigned int w4 = base[(size_t)r4 * 64 + lane];
        unsigned int w5 = base[(size_t)r5 * 64 + lane];
        unsigned int w6 = base[(size_t)r6 * 64 + lane];
        unsigned int w7 = base[(size_t)r7 * 64 + lane];
        ax0 += bflo(v0) + bflo(v1) + bflo(v2) + bflo(v3)
             + bflo(v4) + bflo(v5) + bflo(v6) + bflo(v7);
        ay0 += bfhi(v0) + bfhi(v1) + bfhi(v2) + bfhi(v3)
             + bfhi(v4) + bfhi(v5) + bfhi(v6) + bfhi(v7);
        ax1 += bflo(w0) + bflo(w1) + bflo(w2) + bflo(w3)
             + bflo(w4) + bflo(w5) + bflo(w6) + bflo(w7);
        ay1 += bfhi(w0) + bfhi(w1) + bfhi(w2) + bfhi(w3)
             + bfhi(w4) + bfhi(w5) + bfhi(w6) + bfhi(w7);
        i0 += 8; i1 += 8;
    }
    drain_stream(base, csr_src, i0, e0, lane, ax0, ay0);
    drain_stream(base, csr_src, i1, e1, lane, ax1, ay1);
    ((unsigned int*)hb)[(size_t)n0 * 64 + lane]       = packbf(ax0, ay0);
    ((unsigned int*)hb)[(size_t)(n0 + 1) * 64 + lane] = packbf(ax1, ay1);
}

// ---------------- fused layer: out = relu(relu(BN(in@W1))@W2 + b2) ----------------
// R9 structure + W2 register prefetch (proven, unchanged). Used for layers 1,2.
__global__ __launch_bounds__(512, 4) void fused_gemm(const ushort* __restrict__ in,
                                                     ushort* __restrict__ out,
                                                     const ushort* __restrict__ Wt1,
                                                     const ushort* __restrict__ Wt2,
                                                     const float* __restrict__ fold1,
                                                     const float* __restrict__ fold2) {
    __shared__ ushort As[128 * 136];    // A tile -> H tile -> C tile (aliased)
    __shared__ ushort Bs[128 * 136];    // W1^T, then W2^T
    int t = threadIdx.x;
    int row0 = blockIdx.x * 128;        // 782 blocks, last partial (32 rows)

#pragma unroll
    for (int i = 0; i < 4; ++i) {       // stage A + W1
        int f = t + 512 * i; int m = f >> 4, g = f & 15;
        *(float4*)(As + m * 136 + g * 8) = *(const float4*)(in + (size_t)(row0 + m) * D + g * 8);
        *(float4*)(Bs + m * 136 + g * 8) = *(const float4*)(Wt1 + (size_t)m * D + g * 8);
    }
    // W2 prefetch into registers (consumed at restage, after gemm1)
    const uint4* w2v = (const uint4*)Wt2;
    uint4 p0 = w2v[t];
    uint4 p1 = w2v[t + 512];
    uint4 p2 = w2v[t + 1024];
    uint4 p3 = w2v[t + 1536];
    __syncthreads();

    int lane = t & 63, wv = t >> 6;
    int quad = lane >> 4, mr = lane & 15;
    int mbase = wv * 16;
    const ushort* ap = As + (mbase + mr) * 136 + quad * 8;
    bf16x8 a0 = *(const bf16x8*)(ap);
    bf16x8 a1 = *(const bf16x8*)(ap + 32);
    bf16x8 a2 = *(const bf16x8*)(ap + 64);
    bf16x8 a3 = *(const bf16x8*)(ap + 96);

    // --- GEMM1: H = relu(BN(A@W1)) -> As own rows (in-wave DS ordering: safe)
#pragma unroll
    for (int nt = 0; nt < 8; ++nt) {
        const ushort* bq = Bs + (nt * 16 + mr) * 136 + quad * 8;
        bf16x8 b0 = *(const bf16x8*)(bq);
        bf16x8 b1 = *(const bf16x8*)(bq + 32);
        bf16x8 b2 = *(const bf16x8*)(bq + 64);
        bf16x8 b3 = *(const bf16x8*)(bq + 96);
        f32x4 acc = {0.f, 0.f, 0.f, 0.f};
        acc = __builtin_amdgcn_mfma_f32_16x16x32_bf16(a0, b0, acc, 0, 0, 0);
        acc = __builtin_amdgcn_mfma_f32_16x16x32_bf16(a1, b1, acc, 0, 0, 0);
        acc = __builtin_amdgcn_mfma_f32_16x16x32_bf16(a2, b2, acc, 0, 0, 0);
        acc = __builtin_amdgcn_mfma_f32_16x16x32_bf16(a3, b3, acc, 0, 0, 0);
        int j = nt * 16 + mr;           // C/D: col=lane&15, row=quad*4+reg (m89)
        float s = fold1[j], o = fold1[D + j];
#pragma unroll
        for (int r = 0; r < 4; ++r) {
            float z = fmaxf(fmaf(acc[r], s, o), 0.0f);
            As[(mbase + quad * 4 + r) * 136 + j] = f2bf(z);
        }
    }
    __syncthreads();                    // all waves done reading W1 from Bs

    {                                   // restage Bs with prefetched W2 (regs->LDS)
        int f0 = t;          *(uint4*)(Bs + (f0 >> 4) * 136 + (f0 & 15) * 8) = p0;
        int f1 = t + 512;    *(uint4*)(Bs + (f1 >> 4) * 136 + (f1 & 15) * 8) = p1;
        int f2 = t + 1024;   *(uint4*)(Bs + (f2 >> 4) * 136 + (f2 & 15) * 8) = p2;
        int f3 = t + 1536;   *(uint4*)(Bs + (f3 >> 4) * 136 + (f3 & 15) * 8) = p3;
    }
    const ushort* hp = As + (mbase + mr) * 136 + quad * 8;
    bf16x8 h0 = *(const bf16x8*)(hp);
    bf16x8 h1 = *(const bf16x8*)(hp + 32);
    bf16x8 h2 = *(const bf16x8*)(hp + 64);
    bf16x8 h3 = *(const bf16x8*)(hp + 96);
    __syncthreads();                    // W2 staged

    // --- GEMM2: C = relu(H@W2 + b2) -> As own rows
#pragma unroll
    for (int nt = 0; nt < 8; ++nt) {
        const ushort* bq = Bs + (nt * 16 + mr) * 136 + quad * 8;
        bf16x8 b0 = *(const bf16x8*)(bq);
        bf16x8 b1 = *(const bf16x8*)(bq + 32);
        bf16x8 b2 = *(const bf16x8*)(bq + 64);
        bf16x8 b3 = *(const bf16x8*)(bq + 96);
        f32x4 acc = {0.f, 0.f, 0.f, 0.f};
        acc = __builtin_amdgcn_mfma_f32_16x16x32_bf16(h0, b0, acc, 0, 0, 0);
        acc = __builtin_amdgcn_mfma_f32_16x16x32_bf16(h1, b1, acc, 0, 0, 0);
        acc = __builtin_amdgcn_mfma_f32_16x16x32_bf16(h2, b2, acc, 0, 0, 0);
        acc = __builtin_amdgcn_mfma_f32_16x16x32_bf16(h3, b3, acc, 0, 0, 0);
        int j = nt * 16 + mr;
        float o = fold2[D + j];
#pragma unroll
        for (int r = 0; r < 4; ++r) {
            float z = fmaxf(acc[r] + o, 0.0f);
            As[(mbase + quad * 4 + r) * 136 + j] = f2bf(z);
        }
    }
    __syncthreads();

#pragma unroll
    for (int i = 0; i < 8; ++i) {       // coalesced copy-out, float2 = 4 bf16
        int f = t + 512 * i; int lr = f >> 5, g = f & 31;
        if (row0 + lr < N_NODES)
            *(float2*)(out + (size_t)(row0 + lr) * D + g * 4) =
                *(const float2*)(As + lr * 136 + g * 4);
    }
}

// ---------------- layer-3 variant: pool fused into the epilogue (R19) ----------
// gemm3's 25.6MB output is consumed ONLY by global_add_pool -> skip the buf0
// write; pool the C tile straight from LDS into pool[1024][128] fp32 via
// per-graph-segment partial sums + atomicAdd (~530K distributed atomics).
// Same bf16-rounded values + fp32 accumulation as poolhead read-back: no
// accuracy change, minus 25.6MB write and minus poolhead's 25.6MB read.
__global__ __launch_bounds__(512, 4) void fused_gemm_pool(const ushort* __restrict__ in,
                                                          const int* __restrict__ batch,
                                                          float* __restrict__ pool,
                                                          const ushort* __restrict__ Wt1,
                                                          const ushort* __restrict__ Wt2,
                                                          const float* __restrict__ fold1,
                                                          const float* __restrict__ fold2) {
    __shared__ ushort As[128 * 136];
    __shared__ ushort Bs[128 * 136];
    __shared__ int bb[128];             // batch[row0 .. row0+127]
    int t = threadIdx.x;
    int row0 = blockIdx.x * 128;

#pragma unroll
    for (int i = 0; i < 4; ++i) {       // stage A + W1
        int f = t + 512 * i; int m = f >> 4, g = f & 15;
        *(float4*)(As + m * 136 + g * 8) = *(const float4*)(in + (size_t)(row0 + m) * D + g * 8);
        *(float4*)(Bs + m * 136 + g * 8) = *(const float4*)(Wt1 + (size_t)m * D + g * 8);
    }
    const uint4* w2v = (const uint4*)Wt2;
    uint4 p0 = w2v[t];
    uint4 p1 = w2v[t + 512];
    uint4 p2 = w2v[t + 1024];
    uint4 p3 = w2v[t + 1536];
    __syncthreads();

    int lane = t & 63, wv = t >> 6;
    int quad = lane >> 4, mr = lane & 15;
    int mbase = wv * 16;
    const ushort* ap = As + (mbase + mr) * 136 + quad * 8;
    bf16x8 a0 = *(const bf16x8*)(ap);
    bf16x8 a1 = *(const bf16x8*)(ap + 32);
    bf16x8 a2 = *(const bf16x8*)(ap + 64);
    bf16x8 a3 = *(const bf16x8*)(ap + 96);

#pragma unroll
    for (int nt = 0; nt < 8; ++nt) {    // GEMM1 + BN + relu
        const ushort* bq = Bs + (nt * 16 + mr) * 136 + quad * 8;
        bf16x8 b0 = *(const bf16x8*)(bq);
        bf16x8 b1 = *(const bf16x8*)(bq + 32);
        bf16x8 b2 = *(const bf16x8*)(bq + 64);
        bf16x8 b3 = *(const bf16x8*)(bq + 96);
        f32x4 acc = {0.f, 0.f, 0.f, 0.f};
        acc = __builtin_amdgcn_mfma_f32_16x16x32_bf16(a0, b0, acc, 0, 0, 0);
        acc = __builtin_amdgcn_mfma_f32_16x16x32_bf16(a1, b1, acc, 0, 0, 0);
        acc = __builtin_amdgcn_mfma_f32_16x16x32_bf16(a2, b2, acc, 0, 0, 0);
        acc = __builtin_amdgcn_mfma_f32_16x16x32_bf16(a3, b3, acc, 0, 0, 0);
        int j = nt * 16 + mr;
        float s = fold1[j], o = fold1[D + j];
#pragma unroll
        for (int r = 0; r < 4; ++r) {
            float z = fmaxf(fmaf(acc[r], s, o), 0.0f);
            As[(mbase + quad * 4 + r) * 136 + j] = f2bf(z);
        }
    }
    __syncthreads();

    {
        int f0 = t;          *(uint4*)(Bs + (f0 >> 4) * 136 + (f0 & 15) * 8) = p0;
        int f1 = t + 512;    *(uint4*)(Bs + (f1 >> 4) * 136 + (f1 & 15) * 8) = p1;
        int f2 = t + 1024;   *(uint4*)(Bs + (f2 >> 4) * 136 + (f2 & 15) * 8) = p2;
        int f3 = t + 1536;   *(uint4*)(Bs + (f3 >> 4) * 136 + (f3 & 15) * 8) = p3;
    }
    const ushort* hp = As + (mbase + mr) * 136 + quad * 8;
    bf16x8 h0 = *(const bf16x8*)(hp);
    bf16x8 h1 = *(const bf16x8*)(hp + 32);
    bf16x8 h2 = *(const bf16x8*)(hp + 64);
    bf16x8 h3 = *(const bf16x8*)(hp + 96);
    __syncthreads();

#pragma unroll
    for (int nt = 0; nt < 8; ++nt) {    // GEMM2 + bias + relu
        const ushort* bq = Bs + (nt * 16 + mr) * 136 + quad * 8;
        bf16x8 b0 = *(const bf16x8*)(bq);
        bf16x8 b1 = *(const bf16x8*)(bq + 32);
        bf16x8 b2 = *(const bf16x8*)(bq + 64);
        bf16x8 b3 = *(const bf16x8*)(bq + 96);
        f32x4 acc = {0.f, 0.f, 0.f, 0.f};
        acc = __builtin_amdgcn_mfma_f32_16x16x32_bf16(h0, b0, acc, 0, 0, 0);
        acc = __builtin_amdgcn_mfma_f32_16x16x32_bf16(h1, b1, acc, 0, 0, 0);
        acc = __builtin_amdgcn_mfma_f32_16x16x32_bf16(h2, b2, acc, 0, 0, 0);
        acc = __builtin_amdgcn_mfma_f32_16x16x32_bf16(h3, b3, acc, 0, 0, 0);
        int j = nt * 16 + mr;
        float o = fold2[D + j];
#pragma unroll
        for (int r = 0; r < 4; ++r) {
            float z = fmaxf(acc[r] + o, 0.0f);
            As[(mbase + quad * 4 + r) * 136 + j] = f2bf(z);
        }
    }
    if (t < 128)                        // stage batch ids (covered by same barrier)
        bb[t] = (row0 + t < N_NODES) ? batch[row0 + t] : -1;
    __syncthreads();                    // C tile + bb complete

    // ---- pool: 4 row-groups x 128 cols; per-graph partials, one atomic each
    {
        int j = t & 127, rg = t >> 7;
        int rbeg = rg * 32;
        if (row0 + rbeg < N_NODES) {
            int curg = bb[rbeg];
            float s = 0.0f;
#pragma unroll 1
            for (int r = rbeg; r < rbeg + 32; ++r) {
                if (row0 + r >= N_NODES) break;
                int g = bb[r];
                if (g != curg) {
                    atomicAdd(pool + (size_t)curg * D + j, s);
                    s = 0.0f; curg = g;
                }
                s += __uint_as_float((unsigned int)As[r * 136 + j] << 16);
            }
            atomicAdd(pool + (size_t)curg * D + j, s);
        }
    }
}

// ---------------- head: out[r] = relu(pool[r]@W1+b1)@W2+b2 (gemv only) --------
__global__ __launch_bounds__(128) void head_kernel(const float* __restrict__ pool,
                                                   const float* __restrict__ W1,
                                                   const float* __restrict__ b1,
                                                   const float* __restrict__ W2,
                                                   const float* __restrict__ b2,
                                                   float* __restrict__ out) {
    __shared__ float row[128];
    __shared__ float t1[128];
    int r = blockIdx.x, j = threadIdx.x;
    row[j] = pool[(size_t)r * D + j];
    __syncthreads();
    float a1 = b1[j];
    for (int k = 0; k < D; ++k) a1 = fmaf(row[k], W1[k * D + j], a1);
    t1[j] = fmaxf(a1, 0.0f);
    __syncthreads();
    float a2 = b2[j];
    for (int k = 0; k < D; ++k) a2 = fmaf(t1[k], W2[k * D + j], a2);
    out[r * D + j] = a2;
}

// ---------------- launcher ----------------
extern "C" void kernel_launch(void* const* d_in, const int* in_sizes, int n_in,
                              void* d_out, int out_size, void* d_ws, size_t ws_size,
                              hipStream_t stream) {
    const float* x        = (const float*)d_in[0];
    const int*   ei       = (const int*)d_in[1];
    const int*   src      = ei;
    const int*   dst      = ei + N_EDGES;
    const int*   batch    = (const int*)d_in[2];
    const float* conv_W1  = (const float*)d_in[3];
    const float* conv_b1  = (const float*)d_in[4];
    const float* bn_gamma = (const float*)d_in[5];
    const float* bn_beta  = (const float*)d_in[6];
    const float* bn_mean  = (const float*)d_in[7];
    const float* bn_var   = (const float*)d_in[8];
    const float* conv_W2  = (const float*)d_in[9];
    const float* conv_b2  = (const float*)d_in[10];
    const float* head_W1  = (const float*)d_in[11];
    const float* head_b1  = (const float*)d_in[12];
    const float* head_W2  = (const float*)d_in[13];
    const float* head_b2  = (const float*)d_in[14];
    float* out = (float*)d_out;

    char* ws = (char*)d_ws;
    size_t off = 0;
    auto alloc = [&](size_t bytes) -> void* {
        void* p = ws + off;
        off = (off + bytes + 255) & ~(size_t)255;
        return p;
    };
    const size_t NODE_BUF = (size_t)(N_NODES + 128) * D * sizeof(ushort);
    ushort* buf0    = (ushort*)alloc(NODE_BUF);
    ushort* buf1    = (ushort*)alloc(NODE_BUF);
    ushort* Wt      = (ushort*)alloc((size_t)6 * D * D * sizeof(ushort));
    float*  folds   = (float*)alloc((size_t)6 * 2 * D * sizeof(float));
    unsigned int* squeue = (unsigned int*)alloc((size_t)FNSLICE * FSLICE_CAP * sizeof(unsigned int));
    int*   csr_src  = (int*)alloc((size_t)(N_EDGES + 64) * sizeof(int));
    int*   offsets  = (int*)alloc((size_t)(N_NODES + 1) * sizeof(int));
    int*   slice_tail = (int*)alloc((size_t)FNSLICE * sizeof(int));
    float* pool     = (float*)alloc((size_t)N_GRAPHS * D * sizeof(float));

    hipMemsetAsync(slice_tail, 0, FNSLICE * sizeof(int), stream);
    setup_kernel<<<SETUP_GRID, 256, 0, stream>>>(
        x, buf0, conv_W1, conv_W2, Wt,
        conv_b1, bn_gamma, bn_beta, bn_mean, bn_var, conv_b2, folds, pool,
        slice_tail, offsets, src, dst, squeue);
    fill_local<<<FNSLICE, 1024, 0, stream>>>(squeue, slice_tail, offsets, csr_src);

    const int FUSED_GRID = (N_NODES + 127) / 128;   // 782
    for (int l = 0; l < 2; ++l) {
        gather_bf16<<<GATHER_GRID, 256, 0, stream>>>(buf0, offsets, csr_src, buf1);
        fused_gemm<<<FUSED_GRID, 512, 0, stream>>>(buf1, buf0,
            Wt + (size_t)(2 * l) * D * D, Wt + (size_t)(2 * l + 1) * D * D,
            folds + (size_t)(2 * l) * 2 * D, folds + (size_t)(2 * l + 1) * 2 * D);
    }
    gather_bf16<<<GATHER_GRID, 256, 0, stream>>>(buf0, offsets, csr_src, buf1);
    fused_gemm_pool<<<FUSED_GRID, 512, 0, stream>>>(buf1, batch, pool,
        Wt + (size_t)4 * D * D, Wt + (size_t)5 * D * D,
        folds + (size_t)4 * 2 * D, folds + (size_t)5 * 2 * D);

    head_kernel<<<N_GRAPHS, 128, 0, stream>>>(pool, head_W1, head_b1,
                                              head_W2, head_b2, out);
}

// Round 8
// 409.088 us; speedup vs baseline: 7.0151x; 1.0057x over previous
//
#include <hip/hip_runtime.h>

#define N_NODES  100000
#define N_EDGES  1600000
#define N_GRAPHS 1024
#define D        128
#define BN_EPS   1e-5f

// --- atomic-free CSR build geometry ---
#define FNSLICE      98                  // ceil(100000/1024) node slices
#define FSLICE_NODES 1024                // nodes per slice (d>>10)
#define FSLICE_CAP   20480               // queue cap: mean 16384, sigma~127
#define QCAP         96                  // per-block LDS bin: mean 41, +12 sigma
#define CCHUNK       4000
#define CGRID        400                 // 400*4000 == N_EDGES

// --- setup_kernel block ranges (256 thr each) ---
#define CVT_BLOCKS   6250                // 100000*128 / (256*8)
#define PW_BLOCKS    384                 // 6*128*128 / 256
#define FOLD_BLOCKS  3                   // 6*128 / 256
#define PZ_BLOCKS    128                 // 1024*128 floats / (256*4/float4)
#define PZ_BASE      (CVT_BLOCKS + PW_BLOCKS + FOLD_BLOCKS)
#define MISC_BASE    (PZ_BASE + PZ_BLOCKS)
#define COMPACT_BASE (MISC_BASE + 1)
#define SETUP_GRID   (COMPACT_BASE + CGRID)

#define GATHER_GRID  12500               // 12500 blk * 4 waves * 2 nodes = 100000
#define N_TILES      1563                // ceil(100000/64) 64-row gemm tiles

typedef short bf16x8 __attribute__((ext_vector_type(8)));
typedef float f32x4  __attribute__((ext_vector_type(4)));

__device__ __forceinline__ ushort f2bf(float f) {        // RNE fp32->bf16
    unsigned int b = __float_as_uint(f);
    return (ushort)((b + 0x7fffu + ((b >> 16) & 1u)) >> 16);
}
__device__ __forceinline__ float bflo(unsigned int u) { return __uint_as_float(u << 16); }
__device__ __forceinline__ float bfhi(unsigned int u) { return __uint_as_float(u & 0xffff0000u); }
__device__ __forceinline__ unsigned int packbf(float x, float y) {
    return (unsigned int)f2bf(x) | ((unsigned int)f2bf(y) << 16);
}

// ---------------- setup: cvt_x + prep_w + folds + pool-zero + misc + compact ----
__global__ __launch_bounds__(256) void setup_kernel(
        const float* __restrict__ x, ushort* __restrict__ xb,
        const float* __restrict__ W1, const float* __restrict__ W2,
        ushort* __restrict__ Wt,
        const float* __restrict__ b1, const float* __restrict__ gamma,
        const float* __restrict__ beta, const float* __restrict__ mean,
        const float* __restrict__ var, const float* __restrict__ b2,
        float* __restrict__ folds, float* __restrict__ pool,
        int* __restrict__ slice_tail, int* __restrict__ offsets,
        const int* __restrict__ src, const int* __restrict__ dst,
        unsigned int* __restrict__ squeue) {
    __shared__ unsigned int qbuf[FNSLICE * QCAP];   // 37.6 KB (compact range)
    __shared__ int qcnt[FNSLICE];
    __shared__ int qbase[FNSLICE];
    int b = blockIdx.x, t = threadIdx.x;
    if (b < CVT_BLOCKS) {                                  // x -> bf16
        size_t i = ((size_t)b * 256 + t) * 8;
        float4 v0 = *(const float4*)(x + i);
        float4 v1 = *(const float4*)(x + i + 4);
        uint4 o;
        o.x = packbf(v0.x, v0.y); o.y = packbf(v0.z, v0.w);
        o.z = packbf(v1.x, v1.y); o.w = packbf(v1.z, v1.w);
        *(uint4*)(xb + i) = o;
    } else if (b < CVT_BLOCKS + PW_BLOCKS) {               // W -> bf16 transposed
        int idx = (b - CVT_BLOCKS) * 256 + t;              // [0, 6*16384)
        int i = idx >> 14, r = idx & 16383;
        int n = r >> 7, k = r & 127, l = i >> 1;
        const float* W = (i & 1) ? (W2 + (size_t)l * D * D) : (W1 + (size_t)l * D * D);
        Wt[idx] = f2bf(W[k * D + n]);
    } else if (b < PZ_BASE) {                              // BN folds
        int idx = (b - CVT_BLOCKS - PW_BLOCKS) * 256 + t;  // [0, 768)
        if (idx < 6 * D) {
            int i = idx >> 7, j = idx & 127, l = i >> 1;
            float s, o;
            if ((i & 1) == 0) {
                float sv = gamma[l * D + j] * rsqrtf(var[l * D + j] + BN_EPS);
                s = sv;
                o = (b1[l * D + j] - mean[l * D + j]) * sv + beta[l * D + j];
            } else {
                s = 1.0f;
                o = b2[l * D + j];
            }
            folds[(size_t)i * 2 * D + j]     = s;
            folds[(size_t)i * 2 * D + D + j] = o;
        }
    } else if (b < MISC_BASE) {                            // pool-zero (512KB)
        int idx = (b - PZ_BASE) * 256 + t;                 // [0, 32768) float4s
        ((float4*)pool)[idx] = float4{0.f, 0.f, 0.f, 0.f};
    } else if (b == MISC_BASE) {                           // misc
        if (t == 255) offsets[N_NODES] = N_EDGES;
    } else {                                               // compact (CSR pass 1)
        for (int i = t; i < FNSLICE; i += 256) qcnt[i] = 0;
        __syncthreads();
        int e0 = (b - COMPACT_BASE) * CCHUNK;
        int eend = e0 + CCHUNK; if (eend > N_EDGES) eend = N_EDGES;
        for (int e = e0 + t; e < eend; e += 256) {
            int d = dst[e], s = src[e];
            int sl = d >> 10;
            unsigned int pk = ((unsigned int)(d & 1023) << 17) | (unsigned int)s;
            int pos = atomicAdd(&qcnt[sl], 1);
            if (pos < QCAP) qbuf[sl * QCAP + pos] = pk;
            else {  // ~never (12-sigma): direct spill, still correct
                int gp = atomicAdd(&slice_tail[sl], 1);
                squeue[(size_t)sl * FSLICE_CAP + gp] = pk;
            }
        }
        __syncthreads();
        for (int i = t; i < FNSLICE; i += 256) {
            int n = qcnt[i]; if (n > QCAP) n = QCAP;
            qbase[i] = atomicAdd(&slice_tail[i], n);
        }
        __syncthreads();
        int wv = t >> 6, ln = t & 63;
        for (int sl = wv; sl < FNSLICE; sl += 4) {
            int n = qcnt[sl]; if (n > QCAP) n = QCAP;
            int gb = qbase[sl];
            for (int i = ln; i < n; i += 64)
                squeue[(size_t)sl * FSLICE_CAP + gb + i] = qbuf[sl * QCAP + i];
        }
    }
}

// ---------------- CSR pass 2: per-slice hist -> scan -> fill, LDS atomics only ----------------
__global__ __launch_bounds__(1024) void fill_local(const unsigned int* __restrict__ squeue,
                                                   const int* __restrict__ slice_tail,
                                                   int* __restrict__ offsets,
                                                   int* __restrict__ csr_src) {
    __shared__ int hist[FSLICE_NODES];
    __shared__ int cur[FSLICE_NODES];
    __shared__ int sbase[128];
    __shared__ int wsum[16];
    int sl = blockIdx.x, t = threadIdx.x;
    int n = slice_tail[sl];
    if (t < 128) sbase[t] = (t < FNSLICE) ? slice_tail[t] : 0;
    hist[t] = 0;
    __syncthreads();
    for (int off = 1; off < 128; off <<= 1) {      // in-block scan of slice totals
        int u = (t < 128 && t >= off) ? sbase[t - off] : 0;
        __syncthreads();
        if (t < 128) sbase[t] += u;
        __syncthreads();
    }
    int gbase = (sl == 0) ? 0 : sbase[sl - 1];
    size_t qb = (size_t)sl * FSLICE_CAP;
    for (int i = t; i < n; i += 1024)
        atomicAdd(&hist[squeue[qb + i] >> 17], 1);
    __syncthreads();
    int c = hist[t];
    int lane = t & 63, w = t >> 6;
    int sc = c;
#pragma unroll
    for (int off = 1; off < 64; off <<= 1) {       // wave-inclusive scan
        int u = __shfl_up(sc, off, 64);
        if (lane >= off) sc += u;
    }
    if (lane == 63) wsum[w] = sc;
    __syncthreads();
    if (t < 16) {                                  // scan the 16 wave sums
        int ws = wsum[t];
        int s2 = ws;
#pragma unroll
        for (int off = 1; off < 16; off <<= 1) {
            int u = __shfl_up(s2, off, 16);
            if (t >= off) s2 += u;
        }
        wsum[t] = s2 - ws;                         // exclusive wave prefix
    }
    __syncthreads();
    int gslot = gbase + sc + wsum[w] - c;          // global exclusive slot
    cur[t] = gslot;
    int node = sl * FSLICE_NODES + t;
    if (node < N_NODES) offsets[node] = gslot;
    __syncthreads();
    for (int i = t; i < n; i += 1024) {
        unsigned int p = squeue[qb + i];
        int slot = atomicAdd(&cur[p >> 17], 1);    // LDS atomic
        csr_src[slot] = (int)(p & 0x1FFFFu);
    }
}

// Drain one CSR stream with the proven R11 16/4/1 ladder.
__device__ __forceinline__ void drain_stream(const unsigned int* __restrict__ base,
                                             const int* __restrict__ csr,
                                             int i, int e, int lane,
                                             float& ax, float& ay) {
    for (; i + 15 < e; i += 16) {
        int s0 = csr[i],      s1 = csr[i + 1],  s2 = csr[i + 2],  s3 = csr[i + 3];
        int s4 = csr[i + 4],  s5 = csr[i + 5],  s6 = csr[i + 6],  s7 = csr[i + 7];
        int s8 = csr[i + 8],  s9 = csr[i + 9],  sa = csr[i + 10], sb = csr[i + 11];
        int sc = csr[i + 12], sd = csr[i + 13], se = csr[i + 14], sf = csr[i + 15];
        unsigned int v0 = base[(size_t)s0 * 64 + lane];
        unsigned int v1 = base[(size_t)s1 * 64 + lane];
        unsigned int v2 = base[(size_t)s2 * 64 + lane];
        unsigned int v3 = base[(size_t)s3 * 64 + lane];
        unsigned int v4 = base[(size_t)s4 * 64 + lane];
        unsigned int v5 = base[(size_t)s5 * 64 + lane];
        unsigned int v6 = base[(size_t)s6 * 64 + lane];
        unsigned int v7 = base[(size_t)s7 * 64 + lane];
        unsigned int v8 = base[(size_t)s8 * 64 + lane];
        unsigned int v9 = base[(size_t)s9 * 64 + lane];
        unsigned int va = base[(size_t)sa * 64 + lane];
        unsigned int vb = base[(size_t)sb * 64 + lane];
        unsigned int vc = base[(size_t)sc * 64 + lane];
        unsigned int vd = base[(size_t)sd * 64 + lane];
        unsigned int ve = base[(size_t)se * 64 + lane];
        unsigned int vf = base[(size_t)sf * 64 + lane];
        ax += bflo(v0) + bflo(v1) + bflo(v2) + bflo(v3)
            + bflo(v4) + bflo(v5) + bflo(v6) + bflo(v7)
            + bflo(v8) + bflo(v9) + bflo(va) + bflo(vb)
            + bflo(vc) + bflo(vd) + bflo(ve) + bflo(vf);
        ay += bfhi(v0) + bfhi(v1) + bfhi(v2) + bfhi(v3)
            + bfhi(v4) + bfhi(v5) + bfhi(v6) + bfhi(v7)
            + bfhi(v8) + bfhi(v9) + bfhi(va) + bfhi(vb)
            + bfhi(vc) + bfhi(vd) + bfhi(ve) + bfhi(vf);
    }
    for (; i + 3 < e; i += 4) {
        int s0 = csr[i], s1 = csr[i + 1], s2 = csr[i + 2], s3 = csr[i + 3];
        unsigned int v0 = base[(size_t)s0 * 64 + lane];
        unsigned int v1 = base[(size_t)s1 * 64 + lane];
        unsigned int v2 = base[(size_t)s2 * 64 + lane];
        unsigned int v3 = base[(size_t)s3 * 64 + lane];
        ax += bflo(v0) + bflo(v1) + bflo(v2) + bflo(v3);
        ay += bfhi(v0) + bfhi(v1) + bfhi(v2) + bfhi(v3);
    }
    for (; i < e; ++i) {
        unsigned int v = base[(size_t)csr[i] * 64 + lane];
        ax += bflo(v); ay += bfhi(v);
    }
}

// ---------------- aggregation: dual-stream (R18; saturated path, do not re-tune)
__global__ __launch_bounds__(256) void gather_bf16(const ushort* __restrict__ xb,
                                                   const int* __restrict__ offsets,
                                                   const int* __restrict__ csr_src,
                                                   ushort* __restrict__ hb) {
    int wv = threadIdx.x >> 6, lane = threadIdx.x & 63;
    int n0 = (blockIdx.x * 4 + wv) * 2;       // 12500*4*2 == N_NODES
    const unsigned int* base = (const unsigned int*)xb;
    unsigned int u0 = base[(size_t)n0 * 64 + lane];
    unsigned int u1 = base[(size_t)(n0 + 1) * 64 + lane];
    float ax0 = bflo(u0), ay0 = bfhi(u0);
    float ax1 = bflo(u1), ay1 = bfhi(u1);
    int i0 = offsets[n0];
    int e0 = offsets[n0 + 1];
    int i1 = e0;                              // CSR contiguity: offsets[n0+1]
    int e1 = offsets[n0 + 2];
    while (i0 + 7 < e0 && i1 + 7 < e1) {      // dual-8: 16 loads in flight
        int s0 = csr_src[i0],     s1 = csr_src[i0 + 1],
            s2 = csr_src[i0 + 2], s3 = csr_src[i0 + 3];
        int s4 = csr_src[i0 + 4], s5 = csr_src[i0 + 5],
            s6 = csr_src[i0 + 6], s7 = csr_src[i0 + 7];
        int r0 = csr_src[i1],     r1 = csr_src[i1 + 1],
            r2 = csr_src[i1 + 2], r3 = csr_src[i1 + 3];
        int r4 = csr_src[i1 + 4], r5 = csr_src[i1 + 5],
            r6 = csr_src[i1 + 6], r7 = csr_src[i1 + 7];
        unsigned int v0 = base[(size_t)s0 * 64 + lane];
        unsigned int v1 = base[(size_t)s1 * 64 + lane];
        unsigned int v2 = base[(size_t)s2 * 64 + lane];
        unsigned int v3 = base[(size_t)s3 * 64 + lane];
        unsigned int v4 = base[(size_t)s4 * 64 + lane];
        unsigned int v5 = base[(size_t)s5 * 64 + lane];
        unsigned int v6 = base[(size_t)s6 * 64 + lane];
        unsigned int v7 = base[(size_t)s7 * 64 + lane];
        unsigned int w0 = base[(size_t)r0 * 64 + lane];
        unsigned int w1 = base[(size_t)r1 * 64 + lane];
        unsigned int w2 = base[(size_t)r2 * 64 + lane];
        unsigned int w3 = base[(size_t)r3 * 64 + lane];
        unsigned int w4 = base[(size_t)r4 * 64 + lane];
        unsigned int w5 = base[(size_t)r5 * 64 + lane];
        unsigned int w6 = base[(size_t)r6 * 64 + lane];
        unsigned int w7 = base[(size_t)r7 * 64 + lane];
        ax0 += bflo(v0) + bflo(v1) + bflo(v2) + bflo(v3)
             + bflo(v4) + bflo(v5) + bflo(v6) + bflo(v7);
        ay0 += bfhi(v0) + bfhi(v1) + bfhi(v2) + bfhi(v3)
             + bfhi(v4) + bfhi(v5) + bfhi(v6) + bfhi(v7);
        ax1 += bflo(w0) + bflo(w1) + bflo(w2) + bflo(w3)
             + bflo(w4) + bflo(w5) + bflo(w6) + bflo(w7);
        ay1 += bfhi(w0) + bfhi(w1) + bfhi(w2) + bfhi(w3)
             + bfhi(w4) + bfhi(w5) + bfhi(w6) + bfhi(w7);
        i0 += 8; i1 += 8;
    }
    drain_stream(base, csr_src, i0, e0, lane, ax0, ay0);
    drain_stream(base, csr_src, i1, e1, lane, ax1, ay1);
    ((unsigned int*)hb)[(size_t)n0 * 64 + lane]       = packbf(ax0, ay0);
    ((unsigned int*)hb)[(size_t)(n0 + 1) * 64 + lane] = packbf(ax1, ay1);
}

// ---------------- fused layer, 64-row tiles (R20) --------------------------------
// R16-proven geometry ported standalone: LDS 52.2KB -> 3 blocks/CU (24 waves/CU)
// vs the 128-row version's 2. 8 waves as (rb = wv&3 row-block, ch = wv>>2
// col-half); wave PAIRS share A/H rows -> extra barrier after fragment loads.
__global__ __launch_bounds__(512, 6) void fused_gemm(const ushort* __restrict__ in,
                                                     ushort* __restrict__ out,
                                                     const ushort* __restrict__ Wt1,
                                                     const ushort* __restrict__ Wt2,
                                                     const float* __restrict__ fold1,
                                                     const float* __restrict__ fold2) {
    __shared__ ushort As[64 * 136];     // A tile -> H tile -> C tile (aliased)
    __shared__ ushort Bs[128 * 136];    // W1^T, then W2^T
    int t = threadIdx.x;
    int row0 = blockIdx.x * 64;         // 1563 blocks, last partial (32 rows)

#pragma unroll
    for (int i = 0; i < 2; ++i) {       // stage A (64x128)
        int f = t + 512 * i; int m = f >> 4, g = f & 15;
        *(float4*)(As + m * 136 + g * 8) = *(const float4*)(in + (size_t)(row0 + m) * D + g * 8);
    }
#pragma unroll
    for (int i = 0; i < 4; ++i) {       // stage W1 (128x128)
        int f = t + 512 * i; int m = f >> 4, g = f & 15;
        *(float4*)(Bs + m * 136 + g * 8) = *(const float4*)(Wt1 + (size_t)m * D + g * 8);
    }
    const uint4* w2v = (const uint4*)Wt2;          // W2 reg prefetch
    uint4 p0 = w2v[t];
    uint4 p1 = w2v[t + 512];
    uint4 p2 = w2v[t + 1024];
    uint4 p3 = w2v[t + 1536];
    __syncthreads();

    int lane = t & 63, wv = t >> 6;
    int quad = lane >> 4, mr = lane & 15;
    int rb = wv & 3, ch = wv >> 2;
    int rbase = rb * 16;
    const ushort* ap = As + (rbase + mr) * 136 + quad * 8;
    bf16x8 a0 = *(const bf16x8*)(ap);
    bf16x8 a1 = *(const bf16x8*)(ap + 32);
    bf16x8 a2 = *(const bf16x8*)(ap + 64);
    bf16x8 a3 = *(const bf16x8*)(ap + 96);
    __syncthreads();                    // pair wave must finish A-frag loads first

#pragma unroll
    for (int nt4 = 0; nt4 < 4; ++nt4) { // GEMM1 + BN + relu
        int nt = ch * 4 + nt4;
        const ushort* bq = Bs + (nt * 16 + mr) * 136 + quad * 8;
        bf16x8 b0 = *(const bf16x8*)(bq);
        bf16x8 b1 = *(const bf16x8*)(bq + 32);
        bf16x8 b2 = *(const bf16x8*)(bq + 64);
        bf16x8 b3 = *(const bf16x8*)(bq + 96);
        f32x4 acc = {0.f, 0.f, 0.f, 0.f};
        acc = __builtin_amdgcn_mfma_f32_16x16x32_bf16(a0, b0, acc, 0, 0, 0);
        acc = __builtin_amdgcn_mfma_f32_16x16x32_bf16(a1, b1, acc, 0, 0, 0);
        acc = __builtin_amdgcn_mfma_f32_16x16x32_bf16(a2, b2, acc, 0, 0, 0);
        acc = __builtin_amdgcn_mfma_f32_16x16x32_bf16(a3, b3, acc, 0, 0, 0);
        int j = nt * 16 + mr;           // C/D: col=lane&15, row=quad*4+reg (m89)
        float s = fold1[j], o = fold1[D + j];
#pragma unroll
        for (int r = 0; r < 4; ++r) {
            float z = fmaxf(fmaf(acc[r], s, o), 0.0f);
            As[(rbase + quad * 4 + r) * 136 + j] = f2bf(z);
        }
    }
    __syncthreads();                    // all waves done with W1 + H fully written

    {                                   // restage Bs with prefetched W2 (regs->LDS)
        int f0 = t;          *(uint4*)(Bs + (f0 >> 4) * 136 + (f0 & 15) * 8) = p0;
        int f1 = t + 512;    *(uint4*)(Bs + (f1 >> 4) * 136 + (f1 & 15) * 8) = p1;
        int f2 = t + 1024;   *(uint4*)(Bs + (f2 >> 4) * 136 + (f2 & 15) * 8) = p2;
        int f3 = t + 1536;   *(uint4*)(Bs + (f3 >> 4) * 136 + (f3 & 15) * 8) = p3;
    }
    const ushort* hp = As + (rbase + mr) * 136 + quad * 8;
    bf16x8 h0 = *(const bf16x8*)(hp);
    bf16x8 h1 = *(const bf16x8*)(hp + 32);
    bf16x8 h2 = *(const bf16x8*)(hp + 64);
    bf16x8 h3 = *(const bf16x8*)(hp + 96);
    __syncthreads();                    // W2 staged; h-frags loaded before C writes

#pragma unroll
    for (int nt4 = 0; nt4 < 4; ++nt4) { // GEMM2 + bias + relu
        int nt = ch * 4 + nt4;
        const ushort* bq = Bs + (nt * 16 + mr) * 136 + quad * 8;
        bf16x8 b0 = *(const bf16x8*)(bq);
        bf16x8 b1 = *(const bf16x8*)(bq + 32);
        bf16x8 b2 = *(const bf16x8*)(bq + 64);
        bf16x8 b3 = *(const bf16x8*)(bq + 96);
        f32x4 acc = {0.f, 0.f, 0.f, 0.f};
        acc = __builtin_amdgcn_mfma_f32_16x16x32_bf16(h0, b0, acc, 0, 0, 0);
        acc = __builtin_amdgcn_mfma_f32_16x16x32_bf16(h1, b1, acc, 0, 0, 0);
        acc = __builtin_amdgcn_mfma_f32_16x16x32_bf16(h2, b2, acc, 0, 0, 0);
        acc = __builtin_amdgcn_mfma_f32_16x16x32_bf16(h3, b3, acc, 0, 0, 0);
        int j = nt * 16 + mr;
        float o = fold2[D + j];
#pragma unroll
        for (int r = 0; r < 4; ++r) {
            float z = fmaxf(acc[r] + o, 0.0f);
            As[(rbase + quad * 4 + r) * 136 + j] = f2bf(z);
        }
    }
    __syncthreads();

#pragma unroll
    for (int i = 0; i < 4; ++i) {       // coalesced copy-out, float2 = 4 bf16
        int f = t + 512 * i; int lr = f >> 5, g = f & 31;
        if (row0 + lr < N_NODES)
            *(float2*)(out + (size_t)(row0 + lr) * D + g * 4) =
                *(const float2*)(As + lr * 136 + g * 4);
    }
}

// ---------------- layer-3 variant: pool fused into the epilogue, 64-row --------
__global__ __launch_bounds__(512, 6) void fused_gemm_pool(const ushort* __restrict__ in,
                                                          const int* __restrict__ batch,
                                                          float* __restrict__ pool,
                                                          const ushort* __restrict__ Wt1,
                                                          const ushort* __restrict__ Wt2,
                                                          const float* __restrict__ fold1,
                                                          const float* __restrict__ fold2) {
    __shared__ ushort As[64 * 136];
    __shared__ ushort Bs[128 * 136];
    __shared__ int bb[64];              // batch[row0 .. row0+63]
    int t = threadIdx.x;
    int row0 = blockIdx.x * 64;

#pragma unroll
    for (int i = 0; i < 2; ++i) {       // stage A
        int f = t + 512 * i; int m = f >> 4, g = f & 15;
        *(float4*)(As + m * 136 + g * 8) = *(const float4*)(in + (size_t)(row0 + m) * D + g * 8);
    }
#pragma unroll
    for (int i = 0; i < 4; ++i) {       // stage W1
        int f = t + 512 * i; int m = f >> 4, g = f & 15;
        *(float4*)(Bs + m * 136 + g * 8) = *(const float4*)(Wt1 + (size_t)m * D + g * 8);
    }
    const uint4* w2v = (const uint4*)Wt2;
    uint4 p0 = w2v[t];
    uint4 p1 = w2v[t + 512];
    uint4 p2 = w2v[t + 1024];
    uint4 p3 = w2v[t + 1536];
    __syncthreads();

    int lane = t & 63, wv = t >> 6;
    int quad = lane >> 4, mr = lane & 15;
    int rb = wv & 3, ch = wv >> 2;
    int rbase = rb * 16;
    const ushort* ap = As + (rbase + mr) * 136 + quad * 8;
    bf16x8 a0 = *(const bf16x8*)(ap);
    bf16x8 a1 = *(const bf16x8*)(ap + 32);
    bf16x8 a2 = *(const bf16x8*)(ap + 64);
    bf16x8 a3 = *(const bf16x8*)(ap + 96);
    __syncthreads();                    // pair wave A-frag loads done

#pragma unroll
    for (int nt4 = 0; nt4 < 4; ++nt4) { // GEMM1 + BN + relu
        int nt = ch * 4 + nt4;
        const ushort* bq = Bs + (nt * 16 + mr) * 136 + quad * 8;
        bf16x8 b0 = *(const bf16x8*)(bq);
        bf16x8 b1 = *(const bf16x8*)(bq + 32);
        bf16x8 b2 = *(const bf16x8*)(bq + 64);
        bf16x8 b3 = *(const bf16x8*)(bq + 96);
        f32x4 acc = {0.f, 0.f, 0.f, 0.f};
        acc = __builtin_amdgcn_mfma_f32_16x16x32_bf16(a0, b0, acc, 0, 0, 0);
        acc = __builtin_amdgcn_mfma_f32_16x16x32_bf16(a1, b1, acc, 0, 0, 0);
        acc = __builtin_amdgcn_mfma_f32_16x16x32_bf16(a2, b2, acc, 0, 0, 0);
        acc = __builtin_amdgcn_mfma_f32_16x16x32_bf16(a3, b3, acc, 0, 0, 0);
        int j = nt * 16 + mr;
        float s = fold1[j], o = fold1[D + j];
#pragma unroll
        for (int r = 0; r < 4; ++r) {
            float z = fmaxf(fmaf(acc[r], s, o), 0.0f);
            As[(rbase + quad * 4 + r) * 136 + j] = f2bf(z);
        }
    }
    __syncthreads();

    {
        int f0 = t;          *(uint4*)(Bs + (f0 >> 4) * 136 + (f0 & 15) * 8) = p0;
        int f1 = t + 512;    *(uint4*)(Bs + (f1 >> 4) * 136 + (f1 & 15) * 8) = p1;
        int f2 = t + 1024;   *(uint4*)(Bs + (f2 >> 4) * 136 + (f2 & 15) * 8) = p2;
        int f3 = t + 1536;   *(uint4*)(Bs + (f3 >> 4) * 136 + (f3 & 15) * 8) = p3;
    }
    const ushort* hp = As + (rbase + mr) * 136 + quad * 8;
    bf16x8 h0 = *(const bf16x8*)(hp);
    bf16x8 h1 = *(const bf16x8*)(hp + 32);
    bf16x8 h2 = *(const bf16x8*)(hp + 64);
    bf16x8 h3 = *(const bf16x8*)(hp + 96);
    __syncthreads();

#pragma unroll
    for (int nt4 = 0; nt4 < 4; ++nt4) { // GEMM2 + bias + relu
        int nt = ch * 4 + nt4;
        const ushort* bq = Bs + (nt * 16 + mr) * 136 + quad * 8;
        bf16x8 b0 = *(const bf16x8*)(bq);
        bf16x8 b1 = *(const bf16x8*)(bq + 32);
        bf16x8 b2 = *(const bf16x8*)(bq + 64);
        bf16x8 b3 = *(const bf16x8*)(bq + 96);
        f32x4 acc = {0.f, 0.f, 0.f, 0.f};
        acc = __builtin_amdgcn_mfma_f32_16x16x32_bf16(h0, b0, acc, 0, 0, 0);
        acc = __builtin_amdgcn_mfma_f32_16x16x32_bf16(h1, b1, acc, 0, 0, 0);
        acc = __builtin_amdgcn_mfma_f32_16x16x32_bf16(h2, b2, acc, 0, 0, 0);
        acc = __builtin_amdgcn_mfma_f32_16x16x32_bf16(h3, b3, acc, 0, 0, 0);
        int j = nt * 16 + mr;
        float o = fold2[D + j];
#pragma unroll
        for (int r = 0; r < 4; ++r) {
            float z = fmaxf(acc[r] + o, 0.0f);
            As[(rbase + quad * 4 + r) * 136 + j] = f2bf(z);
        }
    }
    if (t < 64)                         // stage batch ids (covered by same barrier)
        bb[t] = (row0 + t < N_NODES) ? batch[row0 + t] : -1;
    __syncthreads();                    // C tile + bb complete

    // ---- pool: 4 row-groups x 16 rows x 128 cols; per-graph partials + atomicAdd
    {
        int j = t & 127, rg = t >> 7;
        int rbeg = rg * 16;
        if (row0 + rbeg < N_NODES) {
            int curg = bb[rbeg];
            float s = 0.0f;
#pragma unroll 1
            for (int r = rbeg; r < rbeg + 16; ++r) {
                int g = bb[r];
                if (g < 0) break;
                if (g != curg) {
                    atomicAdd(pool + (size_t)curg * D + j, s);
                    s = 0.0f; curg = g;
                }
                s += __uint_as_float((unsigned int)As[r * 136 + j] << 16);
            }
            atomicAdd(pool + (size_t)curg * D + j, s);
        }
    }
}

// ---------------- head: out[r] = relu(pool[r]@W1+b1)@W2+b2 (gemv only) --------
__global__ __launch_bounds__(128) void head_kernel(const float* __restrict__ pool,
                                                   const float* __restrict__ W1,
                                                   const float* __restrict__ b1,
                                                   const float* __restrict__ W2,
                                                   const float* __restrict__ b2,
                                                   float* __restrict__ out) {
    __shared__ float row[128];
    __shared__ float t1[128];
    int r = blockIdx.x, j = threadIdx.x;
    row[j] = pool[(size_t)r * D + j];
    __syncthreads();
    float a1 = b1[j];
    for (int k = 0; k < D; ++k) a1 = fmaf(row[k], W1[k * D + j], a1);
    t1[j] = fmaxf(a1, 0.0f);
    __syncthreads();
    float a2 = b2[j];
    for (int k = 0; k < D; ++k) a2 = fmaf(t1[k], W2[k * D + j], a2);
    out[r * D + j] = a2;
}

// ---------------- launcher ----------------
extern "C" void kernel_launch(void* const* d_in, const int* in_sizes, int n_in,
                              void* d_out, int out_size, void* d_ws, size_t ws_size,
                              hipStream_t stream) {
    const float* x        = (const float*)d_in[0];
    const int*   ei       = (const int*)d_in[1];
    const int*   src      = ei;
    const int*   dst      = ei + N_EDGES;
    const int*   batch    = (const int*)d_in[2];
    const float* conv_W1  = (const float*)d_in[3];
    const float* conv_b1  = (const float*)d_in[4];
    const float* bn_gamma = (const float*)d_in[5];
    const float* bn_beta  = (const float*)d_in[6];
    const float* bn_mean  = (const float*)d_in[7];
    const float* bn_var   = (const float*)d_in[8];
    const float* conv_W2  = (const float*)d_in[9];
    const float* conv_b2  = (const float*)d_in[10];
    const float* head_W1  = (const float*)d_in[11];
    const float* head_b1  = (const float*)d_in[12];
    const float* head_W2  = (const float*)d_in[13];
    const float* head_b2  = (const float*)d_in[14];
    float* out = (float*)d_out;

    char* ws = (char*)d_ws;
    size_t off = 0;
    auto alloc = [&](size_t bytes) -> void* {
        void* p = ws + off;
        off = (off + bytes + 255) & ~(size_t)255;
        return p;
    };
    const size_t NODE_BUF = (size_t)(N_NODES + 128) * D * sizeof(ushort);
    ushort* buf0    = (ushort*)alloc(NODE_BUF);
    ushort* buf1    = (ushort*)alloc(NODE_BUF);
    ushort* Wt      = (ushort*)alloc((size_t)6 * D * D * sizeof(ushort));
    float*  folds   = (float*)alloc((size_t)6 * 2 * D * sizeof(float));
    unsigned int* squeue = (unsigned int*)alloc((size_t)FNSLICE * FSLICE_CAP * sizeof(unsigned int));
    int*   csr_src  = (int*)alloc((size_t)(N_EDGES + 64) * sizeof(int));
    int*   offsets  = (int*)alloc((size_t)(N_NODES + 1) * sizeof(int));
    int*   slice_tail = (int*)alloc((size_t)FNSLICE * sizeof(int));
    float* pool     = (float*)alloc((size_t)N_GRAPHS * D * sizeof(float));

    hipMemsetAsync(slice_tail, 0, FNSLICE * sizeof(int), stream);
    setup_kernel<<<SETUP_GRID, 256, 0, stream>>>(
        x, buf0, conv_W1, conv_W2, Wt,
        conv_b1, bn_gamma, bn_beta, bn_mean, bn_var, conv_b2, folds, pool,
        slice_tail, offsets, src, dst, squeue);
    fill_local<<<FNSLICE, 1024, 0, stream>>>(squeue, slice_tail, offsets, csr_src);

    for (int l = 0; l < 2; ++l) {
        gather_bf16<<<GATHER_GRID, 256, 0, stream>>>(buf0, offsets, csr_src, buf1);
        fused_gemm<<<N_TILES, 512, 0, stream>>>(buf1, buf0,
            Wt + (size_t)(2 * l) * D * D, Wt + (size_t)(2 * l + 1) * D * D,
            folds + (size_t)(2 * l) * 2 * D, folds + (size_t)(2 * l + 1) * 2 * D);
    }
    gather_bf16<<<GATHER_GRID, 256, 0, stream>>>(buf0, offsets, csr_src, buf1);
    fused_gemm_pool<<<N_TILES, 512, 0, stream>>>(buf1, batch, pool,
        Wt + (size_t)4 * D * D, Wt + (size_t)5 * D * D,
        folds + (size_t)4 * 2 * D, folds + (size_t)5 * 2 * D);

    head_kernel<<<N_GRAPHS, 128, 0, stream>>>(pool, head_W1, head_b1,
                                              head_W2, head_b2, out);
}